// Round 7
// baseline (233.072 us; speedup 1.0000x reference)
//
#include <hip/hip_runtime.h>
#include <cstdint>
#include <cstddef>

typedef __bf16 bf16;
typedef __bf16 bf16x8 __attribute__((ext_vector_type(8)));
typedef __bf16 bf16x4 __attribute__((ext_vector_type(4)));
typedef _Float16 f16;
typedef _Float16 f16x4 __attribute__((ext_vector_type(4)));
typedef _Float16 f16x8 __attribute__((ext_vector_type(8)));
typedef __fp16 fp16x2 __attribute__((ext_vector_type(2)));
typedef float f32x4 __attribute__((ext_vector_type(4)));

#define DEV static __device__ __forceinline__
#if __has_builtin(__builtin_amdgcn_exp2f)
#define EXP2(x) __builtin_amdgcn_exp2f(x)
#else
#define EXP2(x) exp2f(x)
#endif
#define QSCALE 0.18033688011112042f

DEV float gelu_exact(float v) {
  return 0.5f * v * (1.0f + erff(v * 0.70710678118654752f));
}

// ---- gload_lds staging into linear [ROWS][64]-bf16 LDS tile with chunk
// swizzle c' = c ^ (r&7). Source row-major, stride ldK elems, base (row0,k0).
// Inverse-swizzled SOURCE + swizzled READ (rule 21); LDS dest stays linear.
template <int ROWS>
DEV void stage_swz(bf16* lbase, const bf16* g, int ldK) {
  const int tid = threadIdx.x;
  const int wave = tid >> 6, lane = tid & 63;
  const int r8 = lane >> 3;                 // row within 8-row chunk
  const int c = (lane & 7) ^ r8;            // fetch inverse-swizzled chunk
  const size_t goff = (size_t)r8 * ldK + c * 8;
#pragma unroll
  for (int ch = wave; ch < (ROWS >> 3); ch += 4) {
    __builtin_amdgcn_global_load_lds(
        (const __attribute__((address_space(1))) void*)(g + (size_t)ch * 8 * ldK + goff),
        (__attribute__((address_space(3))) void*)(lbase + ch * 512), 16, 0, 0);
  }
}

// fragment address in swizzled linear tile: row R, logical 16B chunk c (0..7)
DEV int swzi(int R, int c) { return R * 64 + ((c ^ (R & 7)) << 3); }

// ---------------- coalesced weight transpose: W[K,N] fp32 -> Wt[N,K] bf16 ---
// blocks 0..159: 64x64 weight transpose tiles. blocks 160..2207: x fp32->bf16.
__global__ void cvt_w_kernel(const float* __restrict__ qkv_w, bf16* __restrict__ qwt,
                             const float* __restrict__ proj_w, bf16* __restrict__ pwt,
                             const float* __restrict__ f1w, bf16* __restrict__ f1wt,
                             const float* __restrict__ f2w, bf16* __restrict__ f2wt,
                             const float* __restrict__ x, bf16* __restrict__ xb) {
  int blk = blockIdx.x;
  const int tid = threadIdx.x;
  if (blk >= 160) {  // x conversion: 2048 blocks x 2048 elems
    const size_t i = ((size_t)(blk - 160) * 256 + tid) * 8;
    const float4 a0 = *(const float4*)(x + i);
    const float4 a1 = *(const float4*)(x + i + 4);
    bf16x8 v;
    v[0] = (bf16)a0.x; v[1] = (bf16)a0.y; v[2] = (bf16)a0.z; v[3] = (bf16)a0.w;
    v[4] = (bf16)a1.x; v[5] = (bf16)a1.y; v[6] = (bf16)a1.z; v[7] = (bf16)a1.w;
    *(bf16x8*)(xb + i) = v;
    return;
  }
  const float* w; bf16* o; int K, N;
  if (blk < 48)       { w = qkv_w;  o = qwt;  K = 256; N = 768; }
  else if (blk < 64)  { w = proj_w; o = pwt;  K = 256; N = 256; blk -= 48; }
  else if (blk < 112) { w = f1w;    o = f1wt; K = 256; N = 768; blk -= 64; }
  else                { w = f2w;    o = f2wt; K = 768; N = 256; blk -= 112; }
  const int ntiles = N >> 6;
  const int kt = blk / ntiles, nt = blk - kt * ntiles;
  const int k0 = kt * 64, n0 = nt * 64;
  __shared__ float tile[64][65];
#pragma unroll
  for (int j = 0; j < 4; ++j) {  // load: 1024 float4 chunks, coalesced rows
    const int c = j * 256 + tid;
    const int row = c >> 4, c4 = (c & 15) * 4;
    const float4 v = *(const float4*)(w + (size_t)(k0 + row) * N + n0 + c4);
    tile[row][c4] = v.x; tile[row][c4 + 1] = v.y;
    tile[row][c4 + 2] = v.z; tile[row][c4 + 3] = v.w;
  }
  __syncthreads();
#pragma unroll
  for (int j = 0; j < 4; ++j) {  // store: 1024 bf16x4 chunks, coalesced rows
    const int c = j * 256 + tid;
    const int n = c >> 4, k4 = (c & 15) * 4;
    bf16x4 ov;
#pragma unroll
    for (int i = 0; i < 4; ++i) ov[i] = (bf16)tile[k4 + i][n];
    *(bf16x4*)(o + (size_t)(n0 + n) * K + k0 + k4) = ov;
  }
}

// ---------------- QKV GEMM (bf16 A), gload_lds staging ----------------------
__global__ __launch_bounds__(256, 3)
void gemm_qkv_kernel(const bf16* __restrict__ A, const bf16* __restrict__ Wt,
                     const float* __restrict__ bias, bf16* __restrict__ qb,
                     bf16* __restrict__ kb, f16* __restrict__ vt) {
  const int tid = threadIdx.x;
  const int wave = tid >> 6, lane = tid & 63;
  const int quad = lane >> 4, l15 = lane & 15;
  const int m0 = blockIdx.y * 128, n0 = blockIdx.x * 128;
  const int mw = (wave >> 1) * 64, nw = (wave & 1) * 64;
  const int K = 256;

  __shared__ bf16 lA[128 * 64];
  __shared__ bf16 lB[128 * 64];

  f32x4 acc[4][4] = {};

  for (int k0 = 0; k0 < K; k0 += 64) {
    stage_swz<128>(lA, A + (size_t)m0 * K + k0, K);
    stage_swz<128>(lB, Wt + (size_t)n0 * K + k0, K);
    __syncthreads();
#pragma unroll
    for (int ks = 0; ks < 2; ++ks) {
      bf16x8 af[4], bfm[4];
#pragma unroll
      for (int i = 0; i < 4; ++i)
        af[i] = *(const bf16x8*)(lA + swzi(mw + i * 16 + l15, ks * 4 + quad));
#pragma unroll
      for (int j = 0; j < 4; ++j)
        bfm[j] = *(const bf16x8*)(lB + swzi(nw + j * 16 + l15, ks * 4 + quad));
#pragma unroll
      for (int i = 0; i < 4; ++i)
#pragma unroll
        for (int j = 0; j < 4; ++j)
          acc[i][j] = __builtin_amdgcn_mfma_f32_16x16x32_bf16(af[i], bfm[j],
                                                              acc[i][j], 0, 0, 0);
    }
    __syncthreads();
  }

  const bool isV = (n0 >= 512);
#pragma unroll
  for (int i = 0; i < 4; ++i) {
#pragma unroll
    for (int j = 0; j < 4; ++j) {
      const int n = n0 + nw + j * 16 + l15;
      const float bs = bias[n];
      if (isV) {
        const int m = m0 + mw + i * 16 + quad * 4;
        const int b = m >> 12, t = m & 4095;
        const int h = (n >> 6) & 3, d = n & 63;
        const int tp = (t & ~31) | (((t >> 2) & 3) << 3) | (((t >> 4) & 1) << 2);
        f16x4 hv;
#pragma unroll
        for (int r = 0; r < 4; ++r) hv[r] = (f16)(acc[i][j][r] + bs);
        *(f16x4*)(vt + (size_t)((b * 4 + h) * 64 + d) * 4096 + tp) = hv;
      } else {
        const int s = n >> 8, cc = n & 255, h = cc >> 6, d = cc & 63;
#pragma unroll
        for (int r = 0; r < 4; ++r) {
          const int m = m0 + mw + i * 16 + quad * 4 + r;
          const int b = m >> 12, t = m & 4095;
          const float v = acc[i][j][r] + bs;
          const size_t idx = (size_t)((b * 4 + h) * 4096 + t) * 64 + d;
          if (s == 0) qb[idx] = (bf16)(v * QSCALE);
          else        kb[idx] = (bf16)v;
        }
      }
    }
  }
}

// ---------------- flash attention: KV-split (z=2), gload_lds staging --------
// Staging issued right AFTER the barrier into the other dbuf half; the DMA
// drains at the NEXT barrier, so HBM latency hides under the full compute
// phase (m97 pattern). Linear [64][64] LDS + chunk-XOR swizzle (R5-proven).
__global__ __launch_bounds__(256, 2)
void attn_kernel(const bf16* __restrict__ q, const bf16* __restrict__ k,
                 const f16* __restrict__ vt, bf16* __restrict__ o0,
                 bf16* __restrict__ o1, float* __restrict__ pD) {
  const int tid = threadIdx.x;
  const int wave = tid >> 6, lane = tid & 63;
  const int quad = lane >> 4, l15 = lane & 15;
  const int bh = blockIdx.y;
  const int q0 = blockIdx.x * 128;
  const int z = blockIdx.z;
  const int kvbase = z * 2048;
  __shared__ bf16 lK[2][64 * 64];
  __shared__ f16  lV[2][64 * 64];

  bf16x8 qa0[2], qa1[2];
#pragma unroll
  for (int s = 0; s < 2; ++s) {
    const bf16* qp =
        q + ((size_t)bh * 4096 + q0 + wave * 32 + s * 16 + l15) * 64 + quad * 8;
    qa0[s] = *(const bf16x8*)(qp);
    qa1[s] = *(const bf16x8*)(qp + 32);
  }

  // staging source (per-lane, inverse-swizzled chunk)
  const int srow = lane >> 3;              // row within 8-row group
  const int sc = (lane & 7) ^ srow;        // swizzled 16B chunk
  const bf16* kbase = k + ((size_t)bh * 4096 + kvbase) * 64;
  const f16*  vbase = vt + (size_t)bh * 64 * 4096 + kvbase;

#define STAGE_KV(buf, it_)                                                     \
  {                                                                            \
    const bf16* ks_ = kbase + (size_t)(it_) * 4096;                            \
    const f16*  vs_ = vbase + (it_) * 64;                                      \
    _Pragma("unroll")                                                          \
    for (int i_ = 0; i_ < 2; ++i_) {                                           \
      const int r0_ = i_ * 32 + wave * 8;                                      \
      __builtin_amdgcn_global_load_lds(                                        \
          (const __attribute__((address_space(1))) void*)(                     \
              ks_ + (size_t)(r0_ + srow) * 64 + sc * 8),                       \
          (__attribute__((address_space(3))) void*)(lK[buf] + r0_ * 64),       \
          16, 0, 0);                                                           \
      __builtin_amdgcn_global_load_lds(                                        \
          (const __attribute__((address_space(1))) void*)(                     \
              vs_ + (size_t)(r0_ + srow) * 4096 + sc * 8),                     \
          (__attribute__((address_space(3))) void*)(lV[buf] + r0_ * 64),       \
          16, 0, 0);                                                           \
    }                                                                          \
  }

  STAGE_KV(0, 0);

  f32x4 accO[2][4] = {};
  f32x4 accD[2] = {};
  const f16x8 vone8 = {(f16)1.0f, (f16)1.0f, (f16)1.0f, (f16)1.0f,
                       (f16)1.0f, (f16)1.0f, (f16)1.0f, (f16)1.0f};

  for (int it = 0; it < 32; ++it) {
    const int cur = it & 1;
    __syncthreads();                 // drains the in-flight gload_lds (vmcnt 0)
    if (it + 1 < 32) STAGE_KV(cur ^ 1, it + 1);

    f32x4 sf[2][4];
    __builtin_amdgcn_s_setprio(1);
#pragma unroll
    for (int c = 0; c < 4; ++c) {
      const bf16x8 kb0 = *(const bf16x8*)(lK[cur] + swzi(c * 16 + l15, quad));
      const bf16x8 kb1 = *(const bf16x8*)(lK[cur] + swzi(c * 16 + l15, 4 + quad));
#pragma unroll
      for (int s = 0; s < 2; ++s) {
        f32x4 t = {};
        t = __builtin_amdgcn_mfma_f32_16x16x32_bf16(kb0, qa0[s], t, 0, 0, 0);
        t = __builtin_amdgcn_mfma_f32_16x16x32_bf16(kb1, qa1[s], t, 0, 0, 0);
        sf[s][c] = t;
      }
    }
    __builtin_amdgcn_s_setprio(0);

    f16x8 pa[2][2];
#pragma unroll
    for (int s = 0; s < 2; ++s)
#pragma unroll
      for (int c2 = 0; c2 < 2; ++c2) {
        union { fp16x2 h2[4]; f16x8 h8; } u;
        u.h2[0] = __builtin_amdgcn_cvt_pkrtz(EXP2(sf[s][2 * c2][0]),
                                             EXP2(sf[s][2 * c2][1]));
        u.h2[1] = __builtin_amdgcn_cvt_pkrtz(EXP2(sf[s][2 * c2][2]),
                                             EXP2(sf[s][2 * c2][3]));
        u.h2[2] = __builtin_amdgcn_cvt_pkrtz(EXP2(sf[s][2 * c2 + 1][0]),
                                             EXP2(sf[s][2 * c2 + 1][1]));
        u.h2[3] = __builtin_amdgcn_cvt_pkrtz(EXP2(sf[s][2 * c2 + 1][2]),
                                             EXP2(sf[s][2 * c2 + 1][3]));
        pa[s][c2] = u.h8;
      }

    __builtin_amdgcn_s_setprio(1);
#pragma unroll
    for (int s = 0; s < 2; ++s)
#pragma unroll
      for (int c2 = 0; c2 < 2; ++c2)
        accD[s] = __builtin_amdgcn_mfma_f32_16x16x32_f16(pa[s][c2], vone8,
                                                         accD[s], 0, 0, 0);

#pragma unroll
    for (int c2 = 0; c2 < 2; ++c2) {
#pragma unroll
      for (int n = 0; n < 4; ++n) {
        const f16x8 vb =
            *(const f16x8*)(lV[cur] + swzi(n * 16 + l15, c2 * 4 + quad));
#pragma unroll
        for (int s = 0; s < 2; ++s)
          accO[s][n] = __builtin_amdgcn_mfma_f32_16x16x32_f16(pa[s][c2], vb,
                                                              accO[s][n], 0, 0, 0);
      }
    }
    __builtin_amdgcn_s_setprio(0);
  }
#undef STAGE_KV

  bf16* po = z ? o1 : o0;
  const int b = bh >> 2, h = bh & 3;
#pragma unroll
  for (int s = 0; s < 2; ++s) {
    float inv[4];
#pragma unroll
    for (int r = 0; r < 4; ++r) inv[r] = 1.0f / accD[s][r];
#pragma unroll
    for (int r = 0; r < 4; ++r) {
      const int t = q0 + wave * 32 + s * 16 + quad * 4 + r;
      if (l15 == 0) pD[(size_t)(z * 16 + bh) * 4096 + t] = accD[s][r];
#pragma unroll
      for (int n = 0; n < 4; ++n)
        po[(size_t)(b * 4096 + t) * 256 + h * 64 + n * 16 + l15] =
            (bf16)(accO[s][n][r] * inv[r]);
    }
  }
}

// ---------------- FFN1: bf16-A GEMM + gelu, gload_lds staging ---------------
__global__ __launch_bounds__(256, 3)
void gemm_ffn1_kernel(const bf16* __restrict__ A, const bf16* __restrict__ Wt,
                      const float* __restrict__ bias, bf16* __restrict__ ob) {
  const int tid = threadIdx.x;
  const int wave = tid >> 6, lane = tid & 63;
  const int quad = lane >> 4, l15 = lane & 15;
  const int m0 = blockIdx.y * 128, n0 = blockIdx.x * 128;
  const int mw = (wave >> 1) * 64, nw = (wave & 1) * 64;
  const int K = 256;

  __shared__ bf16 lA[128 * 64];
  __shared__ bf16 lB[128 * 64];

  f32x4 acc[4][4] = {};

  for (int k0 = 0; k0 < K; k0 += 64) {
    stage_swz<128>(lA, A + (size_t)m0 * K + k0, K);
    stage_swz<128>(lB, Wt + (size_t)n0 * K + k0, K);
    __syncthreads();
#pragma unroll
    for (int ks = 0; ks < 2; ++ks) {
      bf16x8 af[4], bfm[4];
#pragma unroll
      for (int i = 0; i < 4; ++i)
        af[i] = *(const bf16x8*)(lA + swzi(mw + i * 16 + l15, ks * 4 + quad));
#pragma unroll
      for (int j = 0; j < 4; ++j)
        bfm[j] = *(const bf16x8*)(lB + swzi(nw + j * 16 + l15, ks * 4 + quad));
#pragma unroll
      for (int i = 0; i < 4; ++i)
#pragma unroll
        for (int j = 0; j < 4; ++j)
          acc[i][j] = __builtin_amdgcn_mfma_f32_16x16x32_bf16(af[i], bfm[j],
                                                              acc[i][j], 0, 0, 0);
    }
    __syncthreads();
  }

#pragma unroll
  for (int i = 0; i < 4; ++i) {
#pragma unroll
    for (int j = 0; j < 4; ++j) {
      const int n = n0 + nw + j * 16 + l15;
      const float bs = bias[n];
#pragma unroll
      for (int r = 0; r < 4; ++r) {
        const int m = m0 + mw + i * 16 + quad * 4 + r;
        ob[(size_t)m * 768 + n] = (bf16)gelu_exact(acc[i][j][r] + bs);
      }
    }
  }
}

// ---------------- GEMM + bias + residual + LayerNorm fused ------------------
// 32-row x 256-col tile (full LN rows), grid M/32 = 512. gload_lds staging.
// COMBINE: A = denominator-weighted average of two attention partials,
// blended in regs and ds_written to the swizzled layout (same involution).
template <int KTILES, bool COMBINE, bool RESID_BF16, bool WRITE_F, bool WRITE_B>
__global__ __launch_bounds__(256, 3)
void gemm_ln_kernel(const bf16* __restrict__ A, const bf16* __restrict__ A2,
                    const float* __restrict__ pD, const bf16* __restrict__ Wt,
                    const float* __restrict__ bias, const void* __restrict__ Rv,
                    const float* __restrict__ lw, const float* __restrict__ lb,
                    float* __restrict__ outf, bf16* __restrict__ outb) {
  const int tid = threadIdx.x;
  const int wave = tid >> 6, lane = tid & 63;
  const int quad = lane >> 4, l15 = lane & 15;
  const int m0 = blockIdx.x * 32;
  const int nw = wave * 64;
  const int K = KTILES * 64;
  __shared__ bf16 lA[32 * 64];
  __shared__ bf16 lB[256 * 64];
  __shared__ float lnsum[4][32];
  __shared__ float lnsq[4][32];
  __shared__ float lnstat[32][2];
  f32x4 acc[2][4] = {};

  for (int kt = 0; kt < KTILES; ++kt) {
    const int k0 = kt * 64;
    if constexpr (COMBINE) {
      const int row = tid >> 3, cc = tid & 7;
      const int am = m0 + row;
      const int h = (k0 + cc * 8) >> 6;  // == kt for K=256
      const int ab = am >> 12, at = am & 4095;
      const float d0 = pD[(size_t)(ab * 4 + h) * 4096 + at];
      const float d1 = pD[(size_t)(16 + ab * 4 + h) * 4096 + at];
      const float wsum = 1.0f / (d0 + d1);
      const float w0 = d0 * wsum, w1 = d1 * wsum;
      const bf16x8 a0 = *(const bf16x8*)(A  + (size_t)am * K + k0 + cc * 8);
      const bf16x8 a1 = *(const bf16x8*)(A2 + (size_t)am * K + k0 + cc * 8);
      bf16x8 cv;
#pragma unroll
      for (int i = 0; i < 8; ++i)
        cv[i] = (bf16)((float)a0[i] * w0 + (float)a1[i] * w1);
      *(bf16x8*)(lA + swzi(row, cc)) = cv;
    } else {
      stage_swz<32>(lA, A + (size_t)m0 * K + k0, K);
    }
    stage_swz<256>(lB, Wt + k0, K);
    __syncthreads();
#pragma unroll
    for (int ks = 0; ks < 2; ++ks) {
      bf16x8 af[2], bfm[4];
#pragma unroll
      for (int i = 0; i < 2; ++i)
        af[i] = *(const bf16x8*)(lA + swzi(i * 16 + l15, ks * 4 + quad));
#pragma unroll
      for (int j = 0; j < 4; ++j)
        bfm[j] = *(const bf16x8*)(lB + swzi(nw + j * 16 + l15, ks * 4 + quad));
#pragma unroll
      for (int i = 0; i < 2; ++i)
#pragma unroll
        for (int j = 0; j < 4; ++j)
          acc[i][j] = __builtin_amdgcn_mfma_f32_16x16x32_bf16(af[i], bfm[j],
                                                              acc[i][j], 0, 0, 0);
    }
    __syncthreads();
  }

  float bv[4], lwv[4], lbv[4];
#pragma unroll
  for (int j = 0; j < 4; ++j) {
    const int col = nw + 16 * j + l15;
    bv[j] = bias[col]; lwv[j] = lw[col]; lbv[j] = lb[col];
  }
#pragma unroll
  for (int i = 0; i < 2; ++i) {
    float ps[4] = {}, pq[4] = {};
#pragma unroll
    for (int j = 0; j < 4; ++j) {
#pragma unroll
      for (int r = 0; r < 4; ++r) {
        const int m = m0 + 16 * i + 4 * quad + r;
        const size_t ri = (size_t)m * 256 + nw + 16 * j + l15;
        const float rv = RESID_BF16 ? (float)((const bf16*)Rv)[ri]
                                    : ((const float*)Rv)[ri];
        const float v = acc[i][j][r] + bv[j] + rv;
        acc[i][j][r] = v;
        ps[r] += v;
        pq[r] += v * v;
      }
    }
#pragma unroll
    for (int r = 0; r < 4; ++r) {
#pragma unroll
      for (int mm = 1; mm < 16; mm <<= 1) {
        ps[r] += __shfl_xor(ps[r], mm, 64);
        pq[r] += __shfl_xor(pq[r], mm, 64);
      }
      if (l15 == 0) {
        lnsum[wave][16 * i + 4 * quad + r] = ps[r];
        lnsq[wave][16 * i + 4 * quad + r] = pq[r];
      }
    }
  }
  __syncthreads();
  if (tid < 32) {
    const float s = lnsum[0][tid] + lnsum[1][tid] + lnsum[2][tid] + lnsum[3][tid];
    const float sq = lnsq[0][tid] + lnsq[1][tid] + lnsq[2][tid] + lnsq[3][tid];
    const float mean = s * (1.0f / 256.0f);
    const float var = sq * (1.0f / 256.0f) - mean * mean;
    lnstat[tid][0] = mean;
    lnstat[tid][1] = rsqrtf(var + 1e-5f);
  }
  __syncthreads();
#pragma unroll
  for (int i = 0; i < 2; ++i) {
#pragma unroll
    for (int r = 0; r < 4; ++r) {
      const int row = 16 * i + 4 * quad + r;
      const float mean = lnstat[row][0], rstd = lnstat[row][1];
#pragma unroll
      for (int j = 0; j < 4; ++j) {
        const float ov = (acc[i][j][r] - mean) * rstd * lwv[j] + lbv[j];
        const size_t gi = (size_t)(m0 + row) * 256 + nw + 16 * j + l15;
        if constexpr (WRITE_F) outf[gi] = ov;
        if constexpr (WRITE_B) outb[gi] = (bf16)ov;
      }
    }
  }
}

extern "C" void kernel_launch(void* const* d_in, const int* in_sizes, int n_in,
                              void* d_out, int out_size, void* d_ws, size_t ws_size,
                              hipStream_t stream) {
  const float* x      = (const float*)d_in[0];
  const float* qkv_w  = (const float*)d_in[1];
  const float* qkv_b  = (const float*)d_in[2];
  const float* proj_w = (const float*)d_in[3];
  const float* proj_b = (const float*)d_in[4];
  const float* n1_w   = (const float*)d_in[5];
  const float* n1_b   = (const float*)d_in[6];
  const float* ffn_w1 = (const float*)d_in[7];
  const float* ffn_b1 = (const float*)d_in[8];
  const float* ffn_w2 = (const float*)d_in[9];
  const float* ffn_b2 = (const float*)d_in[10];
  const float* n2_w   = (const float*)d_in[11];
  const float* n2_b   = (const float*)d_in[12];
  float* out = (float*)d_out;

  char* ws = (char*)d_ws;
  bf16*  qwt  = (bf16*)(ws + 0);
  bf16*  pwt  = (bf16*)(ws + 393216);
  bf16*  f1wt = (bf16*)(ws + 524288);
  bf16*  f2wt = (bf16*)(ws + 917504);
  bf16*  qb   = (bf16*)(ws + 1310720);
  bf16*  kb   = (bf16*)(ws + 9699328);
  f16*   vtb  = (f16*)(ws + 18087936);
  bf16*  attn = (bf16*)(ws + 26476544);   // partial O (z=0)
  bf16*  x1b  = (bf16*)(ws + 34865152);
  bf16*  hbuf = (bf16*)(ws + 1310720);    // aliases qb/kb/vtb (dead by FFN1)
  bf16*  xb   = (bf16*)(ws + 34865152);   // aliases x1b (dead after QKV GEMM)
  bf16*  po1  = (bf16*)(ws + 43253760);   // partial O (z=1)
  float* pden = (float*)(ws + 51642368);  // denominators [2][16][4096] f32

  cvt_w_kernel<<<2208, 256, 0, stream>>>(qkv_w, qwt, proj_w, pwt,
                                         ffn_w1, f1wt, ffn_w2, f2wt, x, xb);
  gemm_qkv_kernel<<<dim3(6, 128), 256, 0, stream>>>(xb, qwt, qkv_b, qb, kb, vtb);
  attn_kernel<<<dim3(32, 16, 2), 256, 0, stream>>>(qb, kb, vtb, attn, po1, pden);
  gemm_ln_kernel<4, true, false, false, true><<<512, 256, 0, stream>>>(
      attn, po1, pden, pwt, proj_b, x, n1_w, n1_b, nullptr, x1b);
  gemm_ffn1_kernel<<<dim3(6, 128), 256, 0, stream>>>(x1b, f1wt, ffn_b1, hbuf);
  gemm_ln_kernel<12, false, true, true, false><<<512, 256, 0, stream>>>(
      hbuf, nullptr, nullptr, f2wt, ffn_b2, x1b, n2_w, n2_b, out, nullptr);
}

// Round 8
// 233.040 us; speedup vs baseline: 1.0001x; 1.0001x over previous
//
#include <hip/hip_runtime.h>
#include <cstdint>
#include <cstddef>

typedef __bf16 bf16;
typedef __bf16 bf16x8 __attribute__((ext_vector_type(8)));
typedef __bf16 bf16x4 __attribute__((ext_vector_type(4)));
typedef _Float16 f16;
typedef _Float16 f16x4 __attribute__((ext_vector_type(4)));
typedef _Float16 f16x8 __attribute__((ext_vector_type(8)));
typedef __fp16 fp16x2 __attribute__((ext_vector_type(2)));
typedef float f32x4 __attribute__((ext_vector_type(4)));

#define DEV static __device__ __forceinline__
#if __has_builtin(__builtin_amdgcn_exp2f)
#define EXP2(x) __builtin_amdgcn_exp2f(x)
#else
#define EXP2(x) exp2f(x)
#endif
#define QSCALE 0.18033688011112042f

DEV float gelu_exact(float v) {
  return 0.5f * v * (1.0f + erff(v * 0.70710678118654752f));
}

// ---- gload_lds staging into linear [ROWS][64]-bf16 LDS tile with chunk
// swizzle c' = c ^ (r&7). Source row-major, stride ldK elems, base (row0,k0).
// Inverse-swizzled SOURCE + swizzled READ (rule 21); LDS dest stays linear.
template <int ROWS>
DEV void stage_swz(bf16* lbase, const bf16* g, int ldK) {
  const int tid = threadIdx.x;
  const int wave = tid >> 6, lane = tid & 63;
  const int r8 = lane >> 3;                 // row within 8-row chunk
  const int c = (lane & 7) ^ r8;            // fetch inverse-swizzled chunk
  const size_t goff = (size_t)r8 * ldK + c * 8;
#pragma unroll
  for (int ch = wave; ch < (ROWS >> 3); ch += 4) {
    __builtin_amdgcn_global_load_lds(
        (const __attribute__((address_space(1))) void*)(g + (size_t)ch * 8 * ldK + goff),
        (__attribute__((address_space(3))) void*)(lbase + ch * 512), 16, 0, 0);
  }
}

// fragment address in swizzled linear tile: row R, logical 16B chunk c (0..7)
DEV int swzi(int R, int c) { return R * 64 + ((c ^ (R & 7)) << 3); }

// ---------------- coalesced weight transpose: W[K,N] fp32 -> Wt[N,K] bf16 ---
// blocks 0..159: 64x64 weight transpose tiles. blocks 160..2207: x fp32->bf16.
__global__ void cvt_w_kernel(const float* __restrict__ qkv_w, bf16* __restrict__ qwt,
                             const float* __restrict__ proj_w, bf16* __restrict__ pwt,
                             const float* __restrict__ f1w, bf16* __restrict__ f1wt,
                             const float* __restrict__ f2w, bf16* __restrict__ f2wt,
                             const float* __restrict__ x, bf16* __restrict__ xb) {
  int blk = blockIdx.x;
  const int tid = threadIdx.x;
  if (blk >= 160) {  // x conversion: 2048 blocks x 2048 elems
    const size_t i = ((size_t)(blk - 160) * 256 + tid) * 8;
    const float4 a0 = *(const float4*)(x + i);
    const float4 a1 = *(const float4*)(x + i + 4);
    bf16x8 v;
    v[0] = (bf16)a0.x; v[1] = (bf16)a0.y; v[2] = (bf16)a0.z; v[3] = (bf16)a0.w;
    v[4] = (bf16)a1.x; v[5] = (bf16)a1.y; v[6] = (bf16)a1.z; v[7] = (bf16)a1.w;
    *(bf16x8*)(xb + i) = v;
    return;
  }
  const float* w; bf16* o; int K, N;
  if (blk < 48)       { w = qkv_w;  o = qwt;  K = 256; N = 768; }
  else if (blk < 64)  { w = proj_w; o = pwt;  K = 256; N = 256; blk -= 48; }
  else if (blk < 112) { w = f1w;    o = f1wt; K = 256; N = 768; blk -= 64; }
  else                { w = f2w;    o = f2wt; K = 768; N = 256; blk -= 112; }
  const int ntiles = N >> 6;
  const int kt = blk / ntiles, nt = blk - kt * ntiles;
  const int k0 = kt * 64, n0 = nt * 64;
  __shared__ float tile[64][65];
#pragma unroll
  for (int j = 0; j < 4; ++j) {  // load: 1024 float4 chunks, coalesced rows
    const int c = j * 256 + tid;
    const int row = c >> 4, c4 = (c & 15) * 4;
    const float4 v = *(const float4*)(w + (size_t)(k0 + row) * N + n0 + c4);
    tile[row][c4] = v.x; tile[row][c4 + 1] = v.y;
    tile[row][c4 + 2] = v.z; tile[row][c4 + 3] = v.w;
  }
  __syncthreads();
#pragma unroll
  for (int j = 0; j < 4; ++j) {  // store: 1024 bf16x4 chunks, coalesced rows
    const int c = j * 256 + tid;
    const int n = c >> 4, k4 = (c & 15) * 4;
    bf16x4 ov;
#pragma unroll
    for (int i = 0; i < 4; ++i) ov[i] = (bf16)tile[k4 + i][n];
    *(bf16x4*)(o + (size_t)(n0 + n) * K + k0 + k4) = ov;
  }
}

// ---------------- QKV GEMM (bf16 A), gload_lds staging ----------------------
// Epilogue goes through an LDS transpose tile so ALL q/k/v global writes are
// fully-coalesced 16B-per-lane stores (old path scattered V as 8B pieces at
// 8KB stride and q/k as 2B scalars). Values are bit-identical.
__global__ __launch_bounds__(256, 3)
void gemm_qkv_kernel(const bf16* __restrict__ A, const bf16* __restrict__ Wt,
                     const float* __restrict__ bias, bf16* __restrict__ qb,
                     bf16* __restrict__ kb, f16* __restrict__ vt) {
  const int tid = threadIdx.x;
  const int wave = tid >> 6, lane = tid & 63;
  const int quad = lane >> 4, l15 = lane & 15;
  const int m0 = blockIdx.y * 128, n0 = blockIdx.x * 128;
  const int mw = (wave >> 1) * 64, nw = (wave & 1) * 64;
  const int K = 256;

  __shared__ __align__(16) char smem[128 * 132 * 2];  // loop: lA+lB; epi: ET
  bf16* lA = (bf16*)smem;
  bf16* lB = lA + 128 * 64;

  f32x4 acc[4][4] = {};

  for (int k0 = 0; k0 < K; k0 += 64) {
    stage_swz<128>(lA, A + (size_t)m0 * K + k0, K);
    stage_swz<128>(lB, Wt + (size_t)n0 * K + k0, K);
    __syncthreads();
#pragma unroll
    for (int ks = 0; ks < 2; ++ks) {
      bf16x8 af[4], bfm[4];
#pragma unroll
      for (int i = 0; i < 4; ++i)
        af[i] = *(const bf16x8*)(lA + swzi(mw + i * 16 + l15, ks * 4 + quad));
#pragma unroll
      for (int j = 0; j < 4; ++j)
        bfm[j] = *(const bf16x8*)(lB + swzi(nw + j * 16 + l15, ks * 4 + quad));
#pragma unroll
      for (int i = 0; i < 4; ++i)
#pragma unroll
        for (int j = 0; j < 4; ++j)
          acc[i][j] = __builtin_amdgcn_mfma_f32_16x16x32_bf16(af[i], bfm[j],
                                                              acc[i][j], 0, 0, 0);
    }
    __syncthreads();
  }

  const int b = m0 >> 12, trow = m0 & 4095;
  const bool isV = (n0 >= 512);
  float bv[4];
#pragma unroll
  for (int j = 0; j < 4; ++j) bv[j] = bias[n0 + nw + 16 * j + l15];

  if (isV) {
    // stage as [n 128][t stride 132] f16 (f16x4 stores, 8B-aligned)
    f16* ET = (f16*)smem;
#pragma unroll
    for (int i = 0; i < 4; ++i)
#pragma unroll
      for (int j = 0; j < 4; ++j) {
        const int n = nw + 16 * j + l15, t = mw + 16 * i + quad * 4;
        f16x4 hv;
#pragma unroll
        for (int r = 0; r < 4; ++r) hv[r] = (f16)(acc[i][j][r] + bv[j]);
        *(f16x4*)(ET + n * 132 + t) = hv;
      }
    __syncthreads();
    // coalesced pass: 16 lanes per (h,d) row; lane stores 16B at t''=l4*8.
    // Output position t'' holds value at t = inv_tp(t'') (tp bit-permutes
    // t[4:0] as t' = t3 t2 t4 t1 t0); inverse gathered from LDS.
    const int nr = tid >> 4, l4 = tid & 15;
    const int g32 = l4 >> 2, q8 = l4 & 3;
#pragma unroll
    for (int pass = 0; pass < 8; ++pass) {
      const int n = pass * 16 + nr;
      const int gn = n0 + n;
      const int h = (gn >> 6) & 3, d = gn & 63;
      const f16* srcr = ET + n * 132 + g32 * 32 + q8 * 4;
      const f16x4 lo = *(const f16x4*)(srcr);
      const f16x4 hi = *(const f16x4*)(srcr + 16);
      union { f16x4 h4[2]; f16x8 h8; } u;
      u.h4[0] = lo; u.h4[1] = hi;
      *(f16x8*)(vt + ((size_t)(b * 4 + h) * 64 + d) * 4096 + trow + l4 * 8) =
          u.h8;
    }
  } else {
    // stage as [t 128][n stride 132] bf16 (scalar stores, conflict-free)
    const bool isQ = (n0 < 256);
    const float sc = isQ ? QSCALE : 1.0f;
    bf16* ET = (bf16*)smem;
#pragma unroll
    for (int i = 0; i < 4; ++i)
#pragma unroll
      for (int j = 0; j < 4; ++j) {
        const int n = nw + 16 * j + l15;
#pragma unroll
        for (int r = 0; r < 4; ++r) {
          const int t = mw + 16 * i + quad * 4 + r;
          ET[t * 132 + n] = (bf16)((acc[i][j][r] + bv[j]) * sc);
        }
      }
    __syncthreads();
    bf16* qk = isQ ? qb : kb;
    const int nr = tid >> 4, l4 = tid & 15;
    const int gn = n0 + l4 * 8;
    const int h = (gn >> 6) & 3, d = gn & 63;
#pragma unroll
    for (int pass = 0; pass < 8; ++pass) {
      const int t = pass * 16 + nr;
      const bf16x4 lo = *(const bf16x4*)(ET + t * 132 + l4 * 8);
      const bf16x4 hi = *(const bf16x4*)(ET + t * 132 + l4 * 8 + 4);
      union { bf16x4 h4[2]; bf16x8 h8; } u;
      u.h4[0] = lo; u.h4[1] = hi;
      *(bf16x8*)(qk + ((size_t)(b * 4 + h) * 4096 + trow + t) * 64 + d) = u.h8;
    }
  }
}

// ---------------- flash attention: KV-split (z=2), gload_lds staging --------
// Staging issued right AFTER the barrier into the other dbuf half; the DMA
// drains at the NEXT barrier, so HBM latency hides under the full compute
// phase (m97 pattern). Linear [64][64] LDS + chunk-XOR swizzle (R5-proven).
__global__ __launch_bounds__(256, 2)
void attn_kernel(const bf16* __restrict__ q, const bf16* __restrict__ k,
                 const f16* __restrict__ vt, bf16* __restrict__ o0,
                 bf16* __restrict__ o1, float* __restrict__ pD) {
  const int tid = threadIdx.x;
  const int wave = tid >> 6, lane = tid & 63;
  const int quad = lane >> 4, l15 = lane & 15;
  const int bh = blockIdx.y;
  const int q0 = blockIdx.x * 128;
  const int z = blockIdx.z;
  const int kvbase = z * 2048;
  __shared__ bf16 lK[2][64 * 64];
  __shared__ f16  lV[2][64 * 64];

  bf16x8 qa0[2], qa1[2];
#pragma unroll
  for (int s = 0; s < 2; ++s) {
    const bf16* qp =
        q + ((size_t)bh * 4096 + q0 + wave * 32 + s * 16 + l15) * 64 + quad * 8;
    qa0[s] = *(const bf16x8*)(qp);
    qa1[s] = *(const bf16x8*)(qp + 32);
  }

  // staging source (per-lane, inverse-swizzled chunk)
  const int srow = lane >> 3;              // row within 8-row group
  const int sc = (lane & 7) ^ srow;        // swizzled 16B chunk
  const bf16* kbase = k + ((size_t)bh * 4096 + kvbase) * 64;
  const f16*  vbase = vt + (size_t)bh * 64 * 4096 + kvbase;

#define STAGE_KV(buf, it_)                                                     \
  {                                                                            \
    const bf16* ks_ = kbase + (size_t)(it_) * 4096;                            \
    const f16*  vs_ = vbase + (it_) * 64;                                      \
    _Pragma("unroll")                                                          \
    for (int i_ = 0; i_ < 2; ++i_) {                                           \
      const int r0_ = i_ * 32 + wave * 8;                                      \
      __builtin_amdgcn_global_load_lds(                                        \
          (const __attribute__((address_space(1))) void*)(                     \
              ks_ + (size_t)(r0_ + srow) * 64 + sc * 8),                       \
          (__attribute__((address_space(3))) void*)(lK[buf] + r0_ * 64),       \
          16, 0, 0);                                                           \
      __builtin_amdgcn_global_load_lds(                                        \
          (const __attribute__((address_space(1))) void*)(                     \
              vs_ + (size_t)(r0_ + srow) * 4096 + sc * 8),                     \
          (__attribute__((address_space(3))) void*)(lV[buf] + r0_ * 64),       \
          16, 0, 0);                                                           \
    }                                                                          \
  }

  STAGE_KV(0, 0);

  f32x4 accO[2][4] = {};
  f32x4 accD[2] = {};
  const f16x8 vone8 = {(f16)1.0f, (f16)1.0f, (f16)1.0f, (f16)1.0f,
                       (f16)1.0f, (f16)1.0f, (f16)1.0f, (f16)1.0f};

  for (int it = 0; it < 32; ++it) {
    const int cur = it & 1;
    __syncthreads();                 // drains the in-flight gload_lds (vmcnt 0)
    if (it + 1 < 32) STAGE_KV(cur ^ 1, it + 1);

    f32x4 sf[2][4];
    __builtin_amdgcn_s_setprio(1);
#pragma unroll
    for (int c = 0; c < 4; ++c) {
      const bf16x8 kb0 = *(const bf16x8*)(lK[cur] + swzi(c * 16 + l15, quad));
      const bf16x8 kb1 = *(const bf16x8*)(lK[cur] + swzi(c * 16 + l15, 4 + quad));
#pragma unroll
      for (int s = 0; s < 2; ++s) {
        f32x4 t = {};
        t = __builtin_amdgcn_mfma_f32_16x16x32_bf16(kb0, qa0[s], t, 0, 0, 0);
        t = __builtin_amdgcn_mfma_f32_16x16x32_bf16(kb1, qa1[s], t, 0, 0, 0);
        sf[s][c] = t;
      }
    }
    __builtin_amdgcn_s_setprio(0);

    f16x8 pa[2][2];
#pragma unroll
    for (int s = 0; s < 2; ++s)
#pragma unroll
      for (int c2 = 0; c2 < 2; ++c2) {
        union { fp16x2 h2[4]; f16x8 h8; } u;
        u.h2[0] = __builtin_amdgcn_cvt_pkrtz(EXP2(sf[s][2 * c2][0]),
                                             EXP2(sf[s][2 * c2][1]));
        u.h2[1] = __builtin_amdgcn_cvt_pkrtz(EXP2(sf[s][2 * c2][2]),
                                             EXP2(sf[s][2 * c2][3]));
        u.h2[2] = __builtin_amdgcn_cvt_pkrtz(EXP2(sf[s][2 * c2 + 1][0]),
                                             EXP2(sf[s][2 * c2 + 1][1]));
        u.h2[3] = __builtin_amdgcn_cvt_pkrtz(EXP2(sf[s][2 * c2 + 1][2]),
                                             EXP2(sf[s][2 * c2 + 1][3]));
        pa[s][c2] = u.h8;
      }

    __builtin_amdgcn_s_setprio(1);
#pragma unroll
    for (int s = 0; s < 2; ++s)
#pragma unroll
      for (int c2 = 0; c2 < 2; ++c2)
        accD[s] = __builtin_amdgcn_mfma_f32_16x16x32_f16(pa[s][c2], vone8,
                                                         accD[s], 0, 0, 0);

#pragma unroll
    for (int c2 = 0; c2 < 2; ++c2) {
#pragma unroll
      for (int n = 0; n < 4; ++n) {
        const f16x8 vb =
            *(const f16x8*)(lV[cur] + swzi(n * 16 + l15, c2 * 4 + quad));
#pragma unroll
        for (int s = 0; s < 2; ++s)
          accO[s][n] = __builtin_amdgcn_mfma_f32_16x16x32_f16(pa[s][c2], vb,
                                                              accO[s][n], 0, 0, 0);
      }
    }
    __builtin_amdgcn_s_setprio(0);
  }
#undef STAGE_KV

  bf16* po = z ? o1 : o0;
  const int b = bh >> 2, h = bh & 3;
#pragma unroll
  for (int s = 0; s < 2; ++s) {
    float inv[4];
#pragma unroll
    for (int r = 0; r < 4; ++r) inv[r] = 1.0f / accD[s][r];
#pragma unroll
    for (int r = 0; r < 4; ++r) {
      const int t = q0 + wave * 32 + s * 16 + quad * 4 + r;
      if (l15 == 0) pD[(size_t)(z * 16 + bh) * 4096 + t] = accD[s][r];
#pragma unroll
      for (int n = 0; n < 4; ++n)
        po[(size_t)(b * 4096 + t) * 256 + h * 64 + n * 16 + l15] =
            (bf16)(accO[s][n][r] * inv[r]);
    }
  }
}

// ---------------- FFN1: bf16-A GEMM + gelu, gload_lds staging ---------------
__global__ __launch_bounds__(256, 3)
void gemm_ffn1_kernel(const bf16* __restrict__ A, const bf16* __restrict__ Wt,
                      const float* __restrict__ bias, bf16* __restrict__ ob) {
  const int tid = threadIdx.x;
  const int wave = tid >> 6, lane = tid & 63;
  const int quad = lane >> 4, l15 = lane & 15;
  const int m0 = blockIdx.y * 128, n0 = blockIdx.x * 128;
  const int mw = (wave >> 1) * 64, nw = (wave & 1) * 64;
  const int K = 256;

  __shared__ bf16 lA[128 * 64];
  __shared__ bf16 lB[128 * 64];

  f32x4 acc[4][4] = {};

  for (int k0 = 0; k0 < K; k0 += 64) {
    stage_swz<128>(lA, A + (size_t)m0 * K + k0, K);
    stage_swz<128>(lB, Wt + (size_t)n0 * K + k0, K);
    __syncthreads();
#pragma unroll
    for (int ks = 0; ks < 2; ++ks) {
      bf16x8 af[4], bfm[4];
#pragma unroll
      for (int i = 0; i < 4; ++i)
        af[i] = *(const bf16x8*)(lA + swzi(mw + i * 16 + l15, ks * 4 + quad));
#pragma unroll
      for (int j = 0; j < 4; ++j)
        bfm[j] = *(const bf16x8*)(lB + swzi(nw + j * 16 + l15, ks * 4 + quad));
#pragma unroll
      for (int i = 0; i < 4; ++i)
#pragma unroll
        for (int j = 0; j < 4; ++j)
          acc[i][j] = __builtin_amdgcn_mfma_f32_16x16x32_bf16(af[i], bfm[j],
                                                              acc[i][j], 0, 0, 0);
    }
    __syncthreads();
  }

#pragma unroll
  for (int i = 0; i < 4; ++i) {
#pragma unroll
    for (int j = 0; j < 4; ++j) {
      const int n = n0 + nw + j * 16 + l15;
      const float bs = bias[n];
#pragma unroll
      for (int r = 0; r < 4; ++r) {
        const int m = m0 + mw + i * 16 + quad * 4 + r;
        ob[(size_t)m * 768 + n] = (bf16)gelu_exact(acc[i][j][r] + bs);
      }
    }
  }
}

// ---------------- GEMM + bias + residual + LayerNorm fused ------------------
// 32-row x 256-col tile (full LN rows), grid M/32 = 512. gload_lds staging.
// COMBINE: A = denominator-weighted average of two attention partials,
// blended in regs and ds_written to the swizzled layout (same involution).
template <int KTILES, bool COMBINE, bool RESID_BF16, bool WRITE_F, bool WRITE_B>
__global__ __launch_bounds__(256, 3)
void gemm_ln_kernel(const bf16* __restrict__ A, const bf16* __restrict__ A2,
                    const float* __restrict__ pD, const bf16* __restrict__ Wt,
                    const float* __restrict__ bias, const void* __restrict__ Rv,
                    const float* __restrict__ lw, const float* __restrict__ lb,
                    float* __restrict__ outf, bf16* __restrict__ outb) {
  const int tid = threadIdx.x;
  const int wave = tid >> 6, lane = tid & 63;
  const int quad = lane >> 4, l15 = lane & 15;
  const int m0 = blockIdx.x * 32;
  const int nw = wave * 64;
  const int K = KTILES * 64;
  __shared__ bf16 lA[32 * 64];
  __shared__ bf16 lB[256 * 64];
  __shared__ float lnsum[4][32];
  __shared__ float lnsq[4][32];
  __shared__ float lnstat[32][2];
  f32x4 acc[2][4] = {};

  for (int kt = 0; kt < KTILES; ++kt) {
    const int k0 = kt * 64;
    if constexpr (COMBINE) {
      const int row = tid >> 3, cc = tid & 7;
      const int am = m0 + row;
      const int h = (k0 + cc * 8) >> 6;  // == kt for K=256
      const int ab = am >> 12, at = am & 4095;
      const float d0 = pD[(size_t)(ab * 4 + h) * 4096 + at];
      const float d1 = pD[(size_t)(16 + ab * 4 + h) * 4096 + at];
      const float wsum = 1.0f / (d0 + d1);
      const float w0 = d0 * wsum, w1 = d1 * wsum;
      const bf16x8 a0 = *(const bf16x8*)(A  + (size_t)am * K + k0 + cc * 8);
      const bf16x8 a1 = *(const bf16x8*)(A2 + (size_t)am * K + k0 + cc * 8);
      bf16x8 cv;
#pragma unroll
      for (int i = 0; i < 8; ++i)
        cv[i] = (bf16)((float)a0[i] * w0 + (float)a1[i] * w1);
      *(bf16x8*)(lA + swzi(row, cc)) = cv;
    } else {
      stage_swz<32>(lA, A + (size_t)m0 * K + k0, K);
    }
    stage_swz<256>(lB, Wt + k0, K);
    __syncthreads();
#pragma unroll
    for (int ks = 0; ks < 2; ++ks) {
      bf16x8 af[2], bfm[4];
#pragma unroll
      for (int i = 0; i < 2; ++i)
        af[i] = *(const bf16x8*)(lA + swzi(i * 16 + l15, ks * 4 + quad));
#pragma unroll
      for (int j = 0; j < 4; ++j)
        bfm[j] = *(const bf16x8*)(lB + swzi(nw + j * 16 + l15, ks * 4 + quad));
#pragma unroll
      for (int i = 0; i < 2; ++i)
#pragma unroll
        for (int j = 0; j < 4; ++j)
          acc[i][j] = __builtin_amdgcn_mfma_f32_16x16x32_bf16(af[i], bfm[j],
                                                              acc[i][j], 0, 0, 0);
    }
    __syncthreads();
  }

  float bv[4], lwv[4], lbv[4];
#pragma unroll
  for (int j = 0; j < 4; ++j) {
    const int col = nw + 16 * j + l15;
    bv[j] = bias[col]; lwv[j] = lw[col]; lbv[j] = lb[col];
  }
#pragma unroll
  for (int i = 0; i < 2; ++i) {
    float ps[4] = {}, pq[4] = {};
#pragma unroll
    for (int j = 0; j < 4; ++j) {
#pragma unroll
      for (int r = 0; r < 4; ++r) {
        const int m = m0 + 16 * i + 4 * quad + r;
        const size_t ri = (size_t)m * 256 + nw + 16 * j + l15;
        const float rv = RESID_BF16 ? (float)((const bf16*)Rv)[ri]
                                    : ((const float*)Rv)[ri];
        const float v = acc[i][j][r] + bv[j] + rv;
        acc[i][j][r] = v;
        ps[r] += v;
        pq[r] += v * v;
      }
    }
#pragma unroll
    for (int r = 0; r < 4; ++r) {
#pragma unroll
      for (int mm = 1; mm < 16; mm <<= 1) {
        ps[r] += __shfl_xor(ps[r], mm, 64);
        pq[r] += __shfl_xor(pq[r], mm, 64);
      }
      if (l15 == 0) {
        lnsum[wave][16 * i + 4 * quad + r] = ps[r];
        lnsq[wave][16 * i + 4 * quad + r] = pq[r];
      }
    }
  }
  __syncthreads();
  if (tid < 32) {
    const float s = lnsum[0][tid] + lnsum[1][tid] + lnsum[2][tid] + lnsum[3][tid];
    const float sq = lnsq[0][tid] + lnsq[1][tid] + lnsq[2][tid] + lnsq[3][tid];
    const float mean = s * (1.0f / 256.0f);
    const float var = sq * (1.0f / 256.0f) - mean * mean;
    lnstat[tid][0] = mean;
    lnstat[tid][1] = rsqrtf(var + 1e-5f);
  }
  __syncthreads();
#pragma unroll
  for (int i = 0; i < 2; ++i) {
#pragma unroll
    for (int r = 0; r < 4; ++r) {
      const int row = 16 * i + 4 * quad + r;
      const float mean = lnstat[row][0], rstd = lnstat[row][1];
#pragma unroll
      for (int j = 0; j < 4; ++j) {
        const float ov = (acc[i][j][r] - mean) * rstd * lwv[j] + lbv[j];
        const size_t gi = (size_t)(m0 + row) * 256 + nw + 16 * j + l15;
        if constexpr (WRITE_F) outf[gi] = ov;
        if constexpr (WRITE_B) outb[gi] = (bf16)ov;
      }
    }
  }
}

extern "C" void kernel_launch(void* const* d_in, const int* in_sizes, int n_in,
                              void* d_out, int out_size, void* d_ws, size_t ws_size,
                              hipStream_t stream) {
  const float* x      = (const float*)d_in[0];
  const float* qkv_w  = (const float*)d_in[1];
  const float* qkv_b  = (const float*)d_in[2];
  const float* proj_w = (const float*)d_in[3];
  const float* proj_b = (const float*)d_in[4];
  const float* n1_w   = (const float*)d_in[5];
  const float* n1_b   = (const float*)d_in[6];
  const float* ffn_w1 = (const float*)d_in[7];
  const float* ffn_b1 = (const float*)d_in[8];
  const float* ffn_w2 = (const float*)d_in[9];
  const float* ffn_b2 = (const float*)d_in[10];
  const float* n2_w   = (const float*)d_in[11];
  const float* n2_b   = (const float*)d_in[12];
  float* out = (float*)d_out;

  char* ws = (char*)d_ws;
  bf16*  qwt  = (bf16*)(ws + 0);
  bf16*  pwt  = (bf16*)(ws + 393216);
  bf16*  f1wt = (bf16*)(ws + 524288);
  bf16*  f2wt = (bf16*)(ws + 917504);
  bf16*  qb   = (bf16*)(ws + 1310720);
  bf16*  kb   = (bf16*)(ws + 9699328);
  f16*   vtb  = (f16*)(ws + 18087936);
  bf16*  attn = (bf16*)(ws + 26476544);   // partial O (z=0)
  bf16*  x1b  = (bf16*)(ws + 34865152);
  bf16*  hbuf = (bf16*)(ws + 1310720);    // aliases qb/kb/vtb (dead by FFN1)
  bf16*  xb   = (bf16*)(ws + 34865152);   // aliases x1b (dead after QKV GEMM)
  bf16*  po1  = (bf16*)(ws + 43253760);   // partial O (z=1)
  float* pden = (float*)(ws + 51642368);  // denominators [2][16][4096] f32

  cvt_w_kernel<<<2208, 256, 0, stream>>>(qkv_w, qwt, proj_w, pwt,
                                         ffn_w1, f1wt, ffn_w2, f2wt, x, xb);
  gemm_qkv_kernel<<<dim3(6, 128), 256, 0, stream>>>(xb, qwt, qkv_b, qb, kb, vtb);
  attn_kernel<<<dim3(32, 16, 2), 256, 0, stream>>>(qb, kb, vtb, attn, po1, pden);
  gemm_ln_kernel<4, true, false, false, true><<<512, 256, 0, stream>>>(
      attn, po1, pden, pwt, proj_b, x, n1_w, n1_b, nullptr, x1b);
  gemm_ffn1_kernel<<<dim3(6, 128), 256, 0, stream>>>(x1b, f1wt, ffn_b1, hbuf);
  gemm_ln_kernel<12, false, true, true, false><<<512, 256, 0, stream>>>(
      hbuf, nullptr, nullptr, f2wt, ffn_b2, x1b, n2_w, n2_b, out, nullptr);
}

// Round 9
// 227.784 us; speedup vs baseline: 1.0232x; 1.0231x over previous
//
#include <hip/hip_runtime.h>
#include <cstdint>
#include <cstddef>

typedef __bf16 bf16;
typedef __bf16 bf16x8 __attribute__((ext_vector_type(8)));
typedef __bf16 bf16x4 __attribute__((ext_vector_type(4)));
typedef _Float16 f16;
typedef _Float16 f16x4 __attribute__((ext_vector_type(4)));
typedef _Float16 f16x8 __attribute__((ext_vector_type(8)));
typedef __fp16 fp16x2 __attribute__((ext_vector_type(2)));
typedef float f32x4 __attribute__((ext_vector_type(4)));

#define DEV static __device__ __forceinline__
#if __has_builtin(__builtin_amdgcn_exp2f)
#define EXP2(x) __builtin_amdgcn_exp2f(x)
#else
#define EXP2(x) exp2f(x)
#endif
#define QSCALE 0.18033688011112042f

DEV float gelu_exact(float v) {
  return 0.5f * v * (1.0f + erff(v * 0.70710678118654752f));
}

// ---- gload_lds staging into linear [ROWS][64]-bf16 LDS tile with chunk
// swizzle c' = c ^ (r&7). Inverse-swizzled SOURCE + swizzled READ (rule 21).
template <int ROWS>
DEV void stage_swz(bf16* lbase, const bf16* g, int ldK) {
  const int tid = threadIdx.x;
  const int wave = tid >> 6, lane = tid & 63;
  const int r8 = lane >> 3;                 // row within 8-row chunk
  const int c = (lane & 7) ^ r8;            // fetch inverse-swizzled chunk
  const size_t goff = (size_t)r8 * ldK + c * 8;
#pragma unroll
  for (int ch = wave; ch < (ROWS >> 3); ch += 4) {
    __builtin_amdgcn_global_load_lds(
        (const __attribute__((address_space(1))) void*)(g + (size_t)ch * 8 * ldK + goff),
        (__attribute__((address_space(3))) void*)(lbase + ch * 512), 16, 0, 0);
  }
}

// fragment address in swizzled linear tile: row R, logical 16B chunk c (0..7)
DEV int swzi(int R, int c) { return R * 64 + ((c ^ (R & 7)) << 3); }

// ---------------- coalesced weight transpose: W[K,N] fp32 -> Wt[N,K] bf16 ---
__global__ void cvt_w_kernel(const float* __restrict__ qkv_w, bf16* __restrict__ qwt,
                             const float* __restrict__ proj_w, bf16* __restrict__ pwt,
                             const float* __restrict__ f1w, bf16* __restrict__ f1wt,
                             const float* __restrict__ f2w, bf16* __restrict__ f2wt,
                             const float* __restrict__ x, bf16* __restrict__ xb) {
  int blk = blockIdx.x;
  const int tid = threadIdx.x;
  if (blk >= 160) {  // x conversion: 2048 blocks x 2048 elems
    const size_t i = ((size_t)(blk - 160) * 256 + tid) * 8;
    const float4 a0 = *(const float4*)(x + i);
    const float4 a1 = *(const float4*)(x + i + 4);
    bf16x8 v;
    v[0] = (bf16)a0.x; v[1] = (bf16)a0.y; v[2] = (bf16)a0.z; v[3] = (bf16)a0.w;
    v[4] = (bf16)a1.x; v[5] = (bf16)a1.y; v[6] = (bf16)a1.z; v[7] = (bf16)a1.w;
    *(bf16x8*)(xb + i) = v;
    return;
  }
  const float* w; bf16* o; int K, N;
  if (blk < 48)       { w = qkv_w;  o = qwt;  K = 256; N = 768; }
  else if (blk < 64)  { w = proj_w; o = pwt;  K = 256; N = 256; blk -= 48; }
  else if (blk < 112) { w = f1w;    o = f1wt; K = 256; N = 768; blk -= 64; }
  else                { w = f2w;    o = f2wt; K = 768; N = 256; blk -= 112; }
  const int ntiles = N >> 6;
  const int kt = blk / ntiles, nt = blk - kt * ntiles;
  const int k0 = kt * 64, n0 = nt * 64;
  __shared__ float tile[64][65];
#pragma unroll
  for (int j = 0; j < 4; ++j) {
    const int c = j * 256 + tid;
    const int row = c >> 4, c4 = (c & 15) * 4;
    const float4 v = *(const float4*)(w + (size_t)(k0 + row) * N + n0 + c4);
    tile[row][c4] = v.x; tile[row][c4 + 1] = v.y;
    tile[row][c4 + 2] = v.z; tile[row][c4 + 3] = v.w;
  }
  __syncthreads();
#pragma unroll
  for (int j = 0; j < 4; ++j) {
    const int c = j * 256 + tid;
    const int n = c >> 4, k4 = (c & 15) * 4;
    bf16x4 ov;
#pragma unroll
    for (int i = 0; i < 4; ++i) ov[i] = (bf16)tile[k4 + i][n];
    *(bf16x4*)(o + (size_t)(n0 + n) * K + k0 + k4) = ov;
  }
}

// ---------------- QKV GEMM (bf16 A), gload_lds staging, LDS-transposed epi --
__global__ __launch_bounds__(256, 3)
void gemm_qkv_kernel(const bf16* __restrict__ A, const bf16* __restrict__ Wt,
                     const float* __restrict__ bias, bf16* __restrict__ qb,
                     bf16* __restrict__ kb, f16* __restrict__ vt) {
  const int tid = threadIdx.x;
  const int wave = tid >> 6, lane = tid & 63;
  const int quad = lane >> 4, l15 = lane & 15;
  const int m0 = blockIdx.y * 128, n0 = blockIdx.x * 128;
  const int mw = (wave >> 1) * 64, nw = (wave & 1) * 64;
  const int K = 256;

  __shared__ __align__(16) char smem[128 * 132 * 2];  // loop: lA+lB; epi: ET
  bf16* lA = (bf16*)smem;
  bf16* lB = lA + 128 * 64;

  f32x4 acc[4][4] = {};

  for (int k0 = 0; k0 < K; k0 += 64) {
    stage_swz<128>(lA, A + (size_t)m0 * K + k0, K);
    stage_swz<128>(lB, Wt + (size_t)n0 * K + k0, K);
    __syncthreads();
#pragma unroll
    for (int ks = 0; ks < 2; ++ks) {
      bf16x8 af[4], bfm[4];
#pragma unroll
      for (int i = 0; i < 4; ++i)
        af[i] = *(const bf16x8*)(lA + swzi(mw + i * 16 + l15, ks * 4 + quad));
#pragma unroll
      for (int j = 0; j < 4; ++j)
        bfm[j] = *(const bf16x8*)(lB + swzi(nw + j * 16 + l15, ks * 4 + quad));
#pragma unroll
      for (int i = 0; i < 4; ++i)
#pragma unroll
        for (int j = 0; j < 4; ++j)
          acc[i][j] = __builtin_amdgcn_mfma_f32_16x16x32_bf16(af[i], bfm[j],
                                                              acc[i][j], 0, 0, 0);
    }
    __syncthreads();
  }

  const int b = m0 >> 12, trow = m0 & 4095;
  const bool isV = (n0 >= 512);
  float bv[4];
#pragma unroll
  for (int j = 0; j < 4; ++j) bv[j] = bias[n0 + nw + 16 * j + l15];

  if (isV) {
    f16* ET = (f16*)smem;
#pragma unroll
    for (int i = 0; i < 4; ++i)
#pragma unroll
      for (int j = 0; j < 4; ++j) {
        const int n = nw + 16 * j + l15, t = mw + 16 * i + quad * 4;
        f16x4 hv;
#pragma unroll
        for (int r = 0; r < 4; ++r) hv[r] = (f16)(acc[i][j][r] + bv[j]);
        *(f16x4*)(ET + n * 132 + t) = hv;
      }
    __syncthreads();
    const int nr = tid >> 4, l4 = tid & 15;
    const int g32 = l4 >> 2, q8 = l4 & 3;
#pragma unroll
    for (int pass = 0; pass < 8; ++pass) {
      const int n = pass * 16 + nr;
      const int gn = n0 + n;
      const int h = (gn >> 6) & 3, d = gn & 63;
      const f16* srcr = ET + n * 132 + g32 * 32 + q8 * 4;
      const f16x4 lo = *(const f16x4*)(srcr);
      const f16x4 hi = *(const f16x4*)(srcr + 16);
      union { f16x4 h4[2]; f16x8 h8; } u;
      u.h4[0] = lo; u.h4[1] = hi;
      *(f16x8*)(vt + ((size_t)(b * 4 + h) * 64 + d) * 4096 + trow + l4 * 8) =
          u.h8;
    }
  } else {
    const bool isQ = (n0 < 256);
    const float sc = isQ ? QSCALE : 1.0f;
    bf16* ET = (bf16*)smem;
#pragma unroll
    for (int i = 0; i < 4; ++i)
#pragma unroll
      for (int j = 0; j < 4; ++j) {
        const int n = nw + 16 * j + l15;
#pragma unroll
        for (int r = 0; r < 4; ++r) {
          const int t = mw + 16 * i + quad * 4 + r;
          ET[t * 132 + n] = (bf16)((acc[i][j][r] + bv[j]) * sc);
        }
      }
    __syncthreads();
    bf16* qk = isQ ? qb : kb;
    const int nr = tid >> 4, l4 = tid & 15;
    const int gn = n0 + l4 * 8;
    const int h = (gn >> 6) & 3, d = gn & 63;
#pragma unroll
    for (int pass = 0; pass < 8; ++pass) {
      const int t = pass * 16 + nr;
      const bf16x4 lo = *(const bf16x4*)(ET + t * 132 + l4 * 8);
      const bf16x4 hi = *(const bf16x4*)(ET + t * 132 + l4 * 8 + 4);
      union { bf16x4 h4[2]; bf16x8 h8; } u;
      u.h4[0] = lo; u.h4[1] = hi;
      *(bf16x8*)(qk + ((size_t)(b * 4 + h) * 4096 + trow + t) * 64 + d) = u.h8;
    }
  }
}

// ---------------- flash attention: KV-split (z=2), gload_lds staging --------
__global__ __launch_bounds__(256, 2)
void attn_kernel(const bf16* __restrict__ q, const bf16* __restrict__ k,
                 const f16* __restrict__ vt, bf16* __restrict__ o0,
                 bf16* __restrict__ o1, float* __restrict__ pD) {
  const int tid = threadIdx.x;
  const int wave = tid >> 6, lane = tid & 63;
  const int quad = lane >> 4, l15 = lane & 15;
  const int bh = blockIdx.y;
  const int q0 = blockIdx.x * 128;
  const int z = blockIdx.z;
  const int kvbase = z * 2048;
  __shared__ bf16 lK[2][64 * 64];
  __shared__ f16  lV[2][64 * 64];

  bf16x8 qa0[2], qa1[2];
#pragma unroll
  for (int s = 0; s < 2; ++s) {
    const bf16* qp =
        q + ((size_t)bh * 4096 + q0 + wave * 32 + s * 16 + l15) * 64 + quad * 8;
    qa0[s] = *(const bf16x8*)(qp);
    qa1[s] = *(const bf16x8*)(qp + 32);
  }

  const int srow = lane >> 3;              // row within 8-row group
  const int sc = (lane & 7) ^ srow;        // swizzled 16B chunk
  const bf16* kbase = k + ((size_t)bh * 4096 + kvbase) * 64;
  const f16*  vbase = vt + (size_t)bh * 64 * 4096 + kvbase;

#define STAGE_KV(buf, it_)                                                     \
  {                                                                            \
    const bf16* ks_ = kbase + (size_t)(it_) * 4096;                            \
    const f16*  vs_ = vbase + (it_) * 64;                                      \
    _Pragma("unroll")                                                          \
    for (int i_ = 0; i_ < 2; ++i_) {                                           \
      const int r0_ = i_ * 32 + wave * 8;                                      \
      __builtin_amdgcn_global_load_lds(                                        \
          (const __attribute__((address_space(1))) void*)(                     \
              ks_ + (size_t)(r0_ + srow) * 64 + sc * 8),                       \
          (__attribute__((address_space(3))) void*)(lK[buf] + r0_ * 64),       \
          16, 0, 0);                                                           \
      __builtin_amdgcn_global_load_lds(                                        \
          (const __attribute__((address_space(1))) void*)(                     \
              vs_ + (size_t)(r0_ + srow) * 4096 + sc * 8),                     \
          (__attribute__((address_space(3))) void*)(lV[buf] + r0_ * 64),       \
          16, 0, 0);                                                           \
    }                                                                          \
  }

  STAGE_KV(0, 0);

  f32x4 accO[2][4] = {};
  f32x4 accD[2] = {};
  const f16x8 vone8 = {(f16)1.0f, (f16)1.0f, (f16)1.0f, (f16)1.0f,
                       (f16)1.0f, (f16)1.0f, (f16)1.0f, (f16)1.0f};

  for (int it = 0; it < 32; ++it) {
    const int cur = it & 1;
    __syncthreads();                 // drains the in-flight gload_lds (vmcnt 0)
    if (it + 1 < 32) STAGE_KV(cur ^ 1, it + 1);

    f32x4 sf[2][4];
    __builtin_amdgcn_s_setprio(1);
#pragma unroll
    for (int c = 0; c < 4; ++c) {
      const bf16x8 kb0 = *(const bf16x8*)(lK[cur] + swzi(c * 16 + l15, quad));
      const bf16x8 kb1 = *(const bf16x8*)(lK[cur] + swzi(c * 16 + l15, 4 + quad));
#pragma unroll
      for (int s = 0; s < 2; ++s) {
        f32x4 t = {};
        t = __builtin_amdgcn_mfma_f32_16x16x32_bf16(kb0, qa0[s], t, 0, 0, 0);
        t = __builtin_amdgcn_mfma_f32_16x16x32_bf16(kb1, qa1[s], t, 0, 0, 0);
        sf[s][c] = t;
      }
    }
    __builtin_amdgcn_s_setprio(0);

    f16x8 pa[2][2];
#pragma unroll
    for (int s = 0; s < 2; ++s)
#pragma unroll
      for (int c2 = 0; c2 < 2; ++c2) {
        union { fp16x2 h2[4]; f16x8 h8; } u;
        u.h2[0] = __builtin_amdgcn_cvt_pkrtz(EXP2(sf[s][2 * c2][0]),
                                             EXP2(sf[s][2 * c2][1]));
        u.h2[1] = __builtin_amdgcn_cvt_pkrtz(EXP2(sf[s][2 * c2][2]),
                                             EXP2(sf[s][2 * c2][3]));
        u.h2[2] = __builtin_amdgcn_cvt_pkrtz(EXP2(sf[s][2 * c2 + 1][0]),
                                             EXP2(sf[s][2 * c2 + 1][1]));
        u.h2[3] = __builtin_amdgcn_cvt_pkrtz(EXP2(sf[s][2 * c2 + 1][2]),
                                             EXP2(sf[s][2 * c2 + 1][3]));
        pa[s][c2] = u.h8;
      }

    __builtin_amdgcn_s_setprio(1);
#pragma unroll
    for (int s = 0; s < 2; ++s)
#pragma unroll
      for (int c2 = 0; c2 < 2; ++c2)
        accD[s] = __builtin_amdgcn_mfma_f32_16x16x32_f16(pa[s][c2], vone8,
                                                         accD[s], 0, 0, 0);

#pragma unroll
    for (int c2 = 0; c2 < 2; ++c2) {
#pragma unroll
      for (int n = 0; n < 4; ++n) {
        const f16x8 vb =
            *(const f16x8*)(lV[cur] + swzi(n * 16 + l15, c2 * 4 + quad));
#pragma unroll
        for (int s = 0; s < 2; ++s)
          accO[s][n] = __builtin_amdgcn_mfma_f32_16x16x32_f16(pa[s][c2], vb,
                                                              accO[s][n], 0, 0, 0);
      }
    }
    __builtin_amdgcn_s_setprio(0);
  }
#undef STAGE_KV

  bf16* po = z ? o1 : o0;
  const int b = bh >> 2, h = bh & 3;
#pragma unroll
  for (int s = 0; s < 2; ++s) {
    float inv[4];
#pragma unroll
    for (int r = 0; r < 4; ++r) inv[r] = 1.0f / accD[s][r];
#pragma unroll
    for (int r = 0; r < 4; ++r) {
      const int t = q0 + wave * 32 + s * 16 + quad * 4 + r;
      if (l15 == 0) pD[(size_t)(z * 16 + bh) * 4096 + t] = accD[s][r];
#pragma unroll
      for (int n = 0; n < 4; ++n)
        po[(size_t)(b * 4096 + t) * 256 + h * 64 + n * 16 + l15] =
            (bf16)(accO[s][n][r] * inv[r]);
    }
  }
}

// ---------------- FUSED: proj-GEMM + combine + residual + LN1 + FFN1 --------
// Phase A = gemm_ln<4,COMBINE> (32 rows x 256 cols, full LN rows); LN output
// written to x1b (needed as ln2 residual) AND kept in LDS as four swizzled
// [32][64] k-group tiles. Phase B = FFN1 (gelu(LN @ f1wt + b1)) reading A
// from LDS, streaming f1wt in 2-ktile macro-stages. Removes the separate
// ffn1 dispatch and its A re-read.
__global__ __launch_bounds__(256, 2)
void ln1_ffn1_kernel(const bf16* __restrict__ A, const bf16* __restrict__ A2,
                     const float* __restrict__ pD, const bf16* __restrict__ pwt,
                     const float* __restrict__ pb, const float* __restrict__ xres,
                     const float* __restrict__ lw, const float* __restrict__ lb,
                     bf16* __restrict__ x1b, const bf16* __restrict__ f1wt,
                     const float* __restrict__ f1b, bf16* __restrict__ ob) {
  const int tid = threadIdx.x;
  const int wave = tid >> 6, lane = tid & 63;
  const int quad = lane >> 4, l15 = lane & 15;
  const int m0 = blockIdx.x * 32;
  const int nw = wave * 64;
  __shared__ bf16 lA[32 * 64];
  __shared__ bf16 lB[256 * 64];
  __shared__ bf16 aT[4 * 32 * 64];
  __shared__ float lnsum[4][32];
  __shared__ float lnsq[4][32];
  __shared__ float lnstat[32][2];
  f32x4 acc[2][4] = {};

  // ---- phase A: proj GEMM with inline KV-split combine ----
  for (int kt = 0; kt < 4; ++kt) {
    const int k0 = kt * 64;
    {
      const int row = tid >> 3, cc = tid & 7;
      const int am = m0 + row;
      const int ab = am >> 12, at = am & 4095;
      const float d0 = pD[(size_t)(ab * 4 + kt) * 4096 + at];
      const float d1 = pD[(size_t)(16 + ab * 4 + kt) * 4096 + at];
      const float wsum = 1.0f / (d0 + d1);
      const float w0 = d0 * wsum, w1 = d1 * wsum;
      const bf16x8 a0 = *(const bf16x8*)(A  + (size_t)am * 256 + k0 + cc * 8);
      const bf16x8 a1 = *(const bf16x8*)(A2 + (size_t)am * 256 + k0 + cc * 8);
      bf16x8 cv;
#pragma unroll
      for (int i = 0; i < 8; ++i)
        cv[i] = (bf16)((float)a0[i] * w0 + (float)a1[i] * w1);
      *(bf16x8*)(lA + swzi(row, cc)) = cv;
    }
    stage_swz<256>(lB, pwt + k0, 256);
    __syncthreads();
#pragma unroll
    for (int ks = 0; ks < 2; ++ks) {
      bf16x8 af[2], bfm[4];
#pragma unroll
      for (int i = 0; i < 2; ++i)
        af[i] = *(const bf16x8*)(lA + swzi(i * 16 + l15, ks * 4 + quad));
#pragma unroll
      for (int j = 0; j < 4; ++j)
        bfm[j] = *(const bf16x8*)(lB + swzi(nw + j * 16 + l15, ks * 4 + quad));
#pragma unroll
      for (int i = 0; i < 2; ++i)
#pragma unroll
        for (int j = 0; j < 4; ++j)
          acc[i][j] = __builtin_amdgcn_mfma_f32_16x16x32_bf16(af[i], bfm[j],
                                                              acc[i][j], 0, 0, 0);
    }
    __syncthreads();
  }

  // ---- LN over full 256-col rows ----
  float bv[4], lwv[4], lbv[4];
#pragma unroll
  for (int j = 0; j < 4; ++j) {
    const int col = nw + 16 * j + l15;
    bv[j] = pb[col]; lwv[j] = lw[col]; lbv[j] = lb[col];
  }
#pragma unroll
  for (int i = 0; i < 2; ++i) {
    float ps[4] = {}, pq[4] = {};
#pragma unroll
    for (int j = 0; j < 4; ++j) {
#pragma unroll
      for (int r = 0; r < 4; ++r) {
        const int m = m0 + 16 * i + 4 * quad + r;
        const size_t ri = (size_t)m * 256 + nw + 16 * j + l15;
        const float v = acc[i][j][r] + bv[j] + xres[ri];
        acc[i][j][r] = v;
        ps[r] += v;
        pq[r] += v * v;
      }
    }
#pragma unroll
    for (int r = 0; r < 4; ++r) {
#pragma unroll
      for (int mm = 1; mm < 16; mm <<= 1) {
        ps[r] += __shfl_xor(ps[r], mm, 64);
        pq[r] += __shfl_xor(pq[r], mm, 64);
      }
      if (l15 == 0) {
        lnsum[wave][16 * i + 4 * quad + r] = ps[r];
        lnsq[wave][16 * i + 4 * quad + r] = pq[r];
      }
    }
  }
  __syncthreads();
  if (tid < 32) {
    const float s = lnsum[0][tid] + lnsum[1][tid] + lnsum[2][tid] + lnsum[3][tid];
    const float sq = lnsq[0][tid] + lnsq[1][tid] + lnsq[2][tid] + lnsq[3][tid];
    const float mean = s * (1.0f / 256.0f);
    const float var = sq * (1.0f / 256.0f) - mean * mean;
    lnstat[tid][0] = mean;
    lnstat[tid][1] = rsqrtf(var + 1e-5f);
  }
  __syncthreads();
#pragma unroll
  for (int i = 0; i < 2; ++i) {
#pragma unroll
    for (int r = 0; r < 4; ++r) {
      const int row = 16 * i + 4 * quad + r;
      const float mean = lnstat[row][0], rstd = lnstat[row][1];
#pragma unroll
      for (int j = 0; j < 4; ++j) {
        const float ov = (acc[i][j][r] - mean) * rstd * lwv[j] + lbv[j];
        const bf16 obf = (bf16)ov;
        const size_t gi = (size_t)(m0 + row) * 256 + nw + 16 * j + l15;
        x1b[gi] = obf;                          // ln2 residual (global)
        const int cg = 16 * j + l15;            // col within k-group = wave
        aT[wave * 2048 + row * 64 + ((((cg >> 3) ^ (row & 7))) << 3) + (cg & 7)]
            = obf;                              // FFN1 A operand (LDS)
      }
    }
  }
  __syncthreads();

  // ---- phase B: FFN1 (32 rows x 768 cols, K=256 from LDS) ----
  const int nwB = wave * 32;
#pragma unroll 1
  for (int nt = 0; nt < 6; ++nt) {
    f32x4 acc2[2][2] = {};
    const bf16* Bb = f1wt + (size_t)nt * 128 * 256;
#pragma unroll 1
    for (int kh = 0; kh < 2; ++kh) {
      stage_swz<128>(lB,        Bb + kh * 128, 256);
      stage_swz<128>(lB + 8192, Bb + kh * 128 + 64, 256);
      __syncthreads();
#pragma unroll
      for (int kk = 0; kk < 2; ++kk) {
        const bf16* aTk = aT + (kh * 2 + kk) * 2048;
        const bf16* lbk = lB + kk * 8192;
#pragma unroll
        for (int ks = 0; ks < 2; ++ks) {
          bf16x8 af[2], bfm[2];
#pragma unroll
          for (int i = 0; i < 2; ++i)
            af[i] = *(const bf16x8*)(aTk + swzi(i * 16 + l15, ks * 4 + quad));
#pragma unroll
          for (int j = 0; j < 2; ++j)
            bfm[j] = *(const bf16x8*)(lbk + swzi(nwB + j * 16 + l15, ks * 4 + quad));
#pragma unroll
          for (int i = 0; i < 2; ++i)
#pragma unroll
            for (int j = 0; j < 2; ++j)
              acc2[i][j] = __builtin_amdgcn_mfma_f32_16x16x32_bf16(
                  af[i], bfm[j], acc2[i][j], 0, 0, 0);
        }
      }
      __syncthreads();
    }
#pragma unroll
    for (int j = 0; j < 2; ++j) {
      const int gn = nt * 128 + nwB + 16 * j + l15;
      const float bs = f1b[gn];
#pragma unroll
      for (int i = 0; i < 2; ++i)
#pragma unroll
        for (int r = 0; r < 4; ++r) {
          const int m = m0 + 16 * i + quad * 4 + r;
          ob[(size_t)m * 768 + gn] = (bf16)gelu_exact(acc2[i][j][r] + bs);
        }
    }
  }
}

// ---------------- GEMM + bias + residual + LayerNorm fused (ln2) ------------
template <int KTILES, bool RESID_BF16, bool WRITE_F, bool WRITE_B>
__global__ __launch_bounds__(256, 3)
void gemm_ln_kernel(const bf16* __restrict__ A, const bf16* __restrict__ Wt,
                    const float* __restrict__ bias, const void* __restrict__ Rv,
                    const float* __restrict__ lw, const float* __restrict__ lb,
                    float* __restrict__ outf, bf16* __restrict__ outb) {
  const int tid = threadIdx.x;
  const int wave = tid >> 6, lane = tid & 63;
  const int quad = lane >> 4, l15 = lane & 15;
  const int m0 = blockIdx.x * 32;
  const int nw = wave * 64;
  const int K = KTILES * 64;
  __shared__ bf16 lA[32 * 64];
  __shared__ bf16 lB[256 * 64];
  __shared__ float lnsum[4][32];
  __shared__ float lnsq[4][32];
  __shared__ float lnstat[32][2];
  f32x4 acc[2][4] = {};

  for (int kt = 0; kt < KTILES; ++kt) {
    const int k0 = kt * 64;
    stage_swz<32>(lA, A + (size_t)m0 * K + k0, K);
    stage_swz<256>(lB, Wt + k0, K);
    __syncthreads();
#pragma unroll
    for (int ks = 0; ks < 2; ++ks) {
      bf16x8 af[2], bfm[4];
#pragma unroll
      for (int i = 0; i < 2; ++i)
        af[i] = *(const bf16x8*)(lA + swzi(i * 16 + l15, ks * 4 + quad));
#pragma unroll
      for (int j = 0; j < 4; ++j)
        bfm[j] = *(const bf16x8*)(lB + swzi(nw + j * 16 + l15, ks * 4 + quad));
#pragma unroll
      for (int i = 0; i < 2; ++i)
#pragma unroll
        for (int j = 0; j < 4; ++j)
          acc[i][j] = __builtin_amdgcn_mfma_f32_16x16x32_bf16(af[i], bfm[j],
                                                              acc[i][j], 0, 0, 0);
    }
    __syncthreads();
  }

  float bv[4], lwv[4], lbv[4];
#pragma unroll
  for (int j = 0; j < 4; ++j) {
    const int col = nw + 16 * j + l15;
    bv[j] = bias[col]; lwv[j] = lw[col]; lbv[j] = lb[col];
  }
#pragma unroll
  for (int i = 0; i < 2; ++i) {
    float ps[4] = {}, pq[4] = {};
#pragma unroll
    for (int j = 0; j < 4; ++j) {
#pragma unroll
      for (int r = 0; r < 4; ++r) {
        const int m = m0 + 16 * i + 4 * quad + r;
        const size_t ri = (size_t)m * 256 + nw + 16 * j + l15;
        const float rv = RESID_BF16 ? (float)((const bf16*)Rv)[ri]
                                    : ((const float*)Rv)[ri];
        const float v = acc[i][j][r] + bv[j] + rv;
        acc[i][j][r] = v;
        ps[r] += v;
        pq[r] += v * v;
      }
    }
#pragma unroll
    for (int r = 0; r < 4; ++r) {
#pragma unroll
      for (int mm = 1; mm < 16; mm <<= 1) {
        ps[r] += __shfl_xor(ps[r], mm, 64);
        pq[r] += __shfl_xor(pq[r], mm, 64);
      }
      if (l15 == 0) {
        lnsum[wave][16 * i + 4 * quad + r] = ps[r];
        lnsq[wave][16 * i + 4 * quad + r] = pq[r];
      }
    }
  }
  __syncthreads();
  if (tid < 32) {
    const float s = lnsum[0][tid] + lnsum[1][tid] + lnsum[2][tid] + lnsum[3][tid];
    const float sq = lnsq[0][tid] + lnsq[1][tid] + lnsq[2][tid] + lnsq[3][tid];
    const float mean = s * (1.0f / 256.0f);
    const float var = sq * (1.0f / 256.0f) - mean * mean;
    lnstat[tid][0] = mean;
    lnstat[tid][1] = rsqrtf(var + 1e-5f);
  }
  __syncthreads();
#pragma unroll
  for (int i = 0; i < 2; ++i) {
#pragma unroll
    for (int r = 0; r < 4; ++r) {
      const int row = 16 * i + 4 * quad + r;
      const float mean = lnstat[row][0], rstd = lnstat[row][1];
#pragma unroll
      for (int j = 0; j < 4; ++j) {
        const float ov = (acc[i][j][r] - mean) * rstd * lwv[j] + lbv[j];
        const size_t gi = (size_t)(m0 + row) * 256 + nw + 16 * j + l15;
        if constexpr (WRITE_F) outf[gi] = ov;
        if constexpr (WRITE_B) outb[gi] = (bf16)ov;
      }
    }
  }
}

extern "C" void kernel_launch(void* const* d_in, const int* in_sizes, int n_in,
                              void* d_out, int out_size, void* d_ws, size_t ws_size,
                              hipStream_t stream) {
  const float* x      = (const float*)d_in[0];
  const float* qkv_w  = (const float*)d_in[1];
  const float* qkv_b  = (const float*)d_in[2];
  const float* proj_w = (const float*)d_in[3];
  const float* proj_b = (const float*)d_in[4];
  const float* n1_w   = (const float*)d_in[5];
  const float* n1_b   = (const float*)d_in[6];
  const float* ffn_w1 = (const float*)d_in[7];
  const float* ffn_b1 = (const float*)d_in[8];
  const float* ffn_w2 = (const float*)d_in[9];
  const float* ffn_b2 = (const float*)d_in[10];
  const float* n2_w   = (const float*)d_in[11];
  const float* n2_b   = (const float*)d_in[12];
  float* out = (float*)d_out;

  char* ws = (char*)d_ws;
  bf16*  qwt  = (bf16*)(ws + 0);
  bf16*  pwt  = (bf16*)(ws + 393216);
  bf16*  f1wt = (bf16*)(ws + 524288);
  bf16*  f2wt = (bf16*)(ws + 917504);
  bf16*  qb   = (bf16*)(ws + 1310720);
  bf16*  kb   = (bf16*)(ws + 9699328);
  f16*   vtb  = (f16*)(ws + 18087936);
  bf16*  attn = (bf16*)(ws + 26476544);   // partial O (z=0)
  bf16*  x1b  = (bf16*)(ws + 34865152);
  bf16*  hbuf = (bf16*)(ws + 1310720);    // aliases qb/kb/vtb (dead by FFN1)
  bf16*  xb   = (bf16*)(ws + 34865152);   // aliases x1b (dead after QKV GEMM)
  bf16*  po1  = (bf16*)(ws + 43253760);   // partial O (z=1)
  float* pden = (float*)(ws + 51642368);  // denominators [2][16][4096] f32

  cvt_w_kernel<<<2208, 256, 0, stream>>>(qkv_w, qwt, proj_w, pwt,
                                         ffn_w1, f1wt, ffn_w2, f2wt, x, xb);
  gemm_qkv_kernel<<<dim3(6, 128), 256, 0, stream>>>(xb, qwt, qkv_b, qb, kb, vtb);
  attn_kernel<<<dim3(32, 16, 2), 256, 0, stream>>>(qb, kb, vtb, attn, po1, pden);
  ln1_ffn1_kernel<<<512, 256, 0, stream>>>(attn, po1, pden, pwt, proj_b, x,
                                           n1_w, n1_b, x1b, f1wt, ffn_b1, hbuf);
  gemm_ln_kernel<12, true, true, false><<<512, 256, 0, stream>>>(
      hbuf, f2wt, ffn_b2, x1b, n2_w, n2_b, out, nullptr);
}

// Round 10
// 224.258 us; speedup vs baseline: 1.0393x; 1.0157x over previous
//
#include <hip/hip_runtime.h>
#include <cstdint>
#include <cstddef>

typedef __bf16 bf16;
typedef __bf16 bf16x8 __attribute__((ext_vector_type(8)));
typedef __bf16 bf16x4 __attribute__((ext_vector_type(4)));
typedef _Float16 f16;
typedef _Float16 f16x4 __attribute__((ext_vector_type(4)));
typedef _Float16 f16x8 __attribute__((ext_vector_type(8)));
typedef __fp16 fp16x2 __attribute__((ext_vector_type(2)));
typedef float f32x4 __attribute__((ext_vector_type(4)));

#define DEV static __device__ __forceinline__
#if __has_builtin(__builtin_amdgcn_exp2f)
#define EXP2(x) __builtin_amdgcn_exp2f(x)
#else
#define EXP2(x) exp2f(x)
#endif
#define QSCALE 0.18033688011112042f

DEV float gelu_exact(float v) {
  return 0.5f * v * (1.0f + erff(v * 0.70710678118654752f));
}

// ---- gload_lds staging into linear [ROWS][64]-bf16 LDS tile with chunk
// swizzle c' = c ^ (r&7). Inverse-swizzled SOURCE + swizzled READ (rule 21).
template <int ROWS>
DEV void stage_swz(bf16* lbase, const bf16* g, int ldK) {
  const int tid = threadIdx.x;
  const int wave = tid >> 6, lane = tid & 63;
  const int r8 = lane >> 3;                 // row within 8-row chunk
  const int c = (lane & 7) ^ r8;            // fetch inverse-swizzled chunk
  const size_t goff = (size_t)r8 * ldK + c * 8;
#pragma unroll
  for (int ch = wave; ch < (ROWS >> 3); ch += 4) {
    __builtin_amdgcn_global_load_lds(
        (const __attribute__((address_space(1))) void*)(g + (size_t)ch * 8 * ldK + goff),
        (__attribute__((address_space(3))) void*)(lbase + ch * 512), 16, 0, 0);
  }
}

// fragment address in swizzled linear tile: row R, logical 16B chunk c (0..7)
DEV int swzi(int R, int c) { return R * 64 + ((c ^ (R & 7)) << 3); }

// ---------------- coalesced weight transpose: W[K,N] fp32 -> Wt[N,K] bf16 ---
__global__ void cvt_w_kernel(const float* __restrict__ qkv_w, bf16* __restrict__ qwt,
                             const float* __restrict__ proj_w, bf16* __restrict__ pwt,
                             const float* __restrict__ f1w, bf16* __restrict__ f1wt,
                             const float* __restrict__ f2w, bf16* __restrict__ f2wt,
                             const float* __restrict__ x, bf16* __restrict__ xb) {
  int blk = blockIdx.x;
  const int tid = threadIdx.x;
  if (blk >= 160) {  // x conversion: 2048 blocks x 2048 elems
    const size_t i = ((size_t)(blk - 160) * 256 + tid) * 8;
    const float4 a0 = *(const float4*)(x + i);
    const float4 a1 = *(const float4*)(x + i + 4);
    bf16x8 v;
    v[0] = (bf16)a0.x; v[1] = (bf16)a0.y; v[2] = (bf16)a0.z; v[3] = (bf16)a0.w;
    v[4] = (bf16)a1.x; v[5] = (bf16)a1.y; v[6] = (bf16)a1.z; v[7] = (bf16)a1.w;
    *(bf16x8*)(xb + i) = v;
    return;
  }
  const float* w; bf16* o; int K, N;
  if (blk < 48)       { w = qkv_w;  o = qwt;  K = 256; N = 768; }
  else if (blk < 64)  { w = proj_w; o = pwt;  K = 256; N = 256; blk -= 48; }
  else if (blk < 112) { w = f1w;    o = f1wt; K = 256; N = 768; blk -= 64; }
  else                { w = f2w;    o = f2wt; K = 768; N = 256; blk -= 112; }
  const int ntiles = N >> 6;
  const int kt = blk / ntiles, nt = blk - kt * ntiles;
  const int k0 = kt * 64, n0 = nt * 64;
  __shared__ float tile[64][65];
#pragma unroll
  for (int j = 0; j < 4; ++j) {
    const int c = j * 256 + tid;
    const int row = c >> 4, c4 = (c & 15) * 4;
    const float4 v = *(const float4*)(w + (size_t)(k0 + row) * N + n0 + c4);
    tile[row][c4] = v.x; tile[row][c4 + 1] = v.y;
    tile[row][c4 + 2] = v.z; tile[row][c4 + 3] = v.w;
  }
  __syncthreads();
#pragma unroll
  for (int j = 0; j < 4; ++j) {
    const int c = j * 256 + tid;
    const int n = c >> 4, k4 = (c & 15) * 4;
    bf16x4 ov;
#pragma unroll
    for (int i = 0; i < 4; ++i) ov[i] = (bf16)tile[k4 + i][n];
    *(bf16x4*)(o + (size_t)(n0 + n) * K + k0 + k4) = ov;
  }
}

// ---------------- QKV GEMM (bf16 A), gload_lds staging, LDS-transposed epi --
__global__ __launch_bounds__(256, 3)
void gemm_qkv_kernel(const bf16* __restrict__ A, const bf16* __restrict__ Wt,
                     const float* __restrict__ bias, bf16* __restrict__ qb,
                     bf16* __restrict__ kb, f16* __restrict__ vt) {
  const int tid = threadIdx.x;
  const int wave = tid >> 6, lane = tid & 63;
  const int quad = lane >> 4, l15 = lane & 15;
  const int m0 = blockIdx.y * 128, n0 = blockIdx.x * 128;
  const int mw = (wave >> 1) * 64, nw = (wave & 1) * 64;
  const int K = 256;

  __shared__ __align__(16) char smem[128 * 132 * 2];  // loop: lA+lB; epi: ET
  bf16* lA = (bf16*)smem;
  bf16* lB = lA + 128 * 64;

  f32x4 acc[4][4] = {};

  for (int k0 = 0; k0 < K; k0 += 64) {
    stage_swz<128>(lA, A + (size_t)m0 * K + k0, K);
    stage_swz<128>(lB, Wt + (size_t)n0 * K + k0, K);
    __syncthreads();
#pragma unroll
    for (int ks = 0; ks < 2; ++ks) {
      bf16x8 af[4], bfm[4];
#pragma unroll
      for (int i = 0; i < 4; ++i)
        af[i] = *(const bf16x8*)(lA + swzi(mw + i * 16 + l15, ks * 4 + quad));
#pragma unroll
      for (int j = 0; j < 4; ++j)
        bfm[j] = *(const bf16x8*)(lB + swzi(nw + j * 16 + l15, ks * 4 + quad));
#pragma unroll
      for (int i = 0; i < 4; ++i)
#pragma unroll
        for (int j = 0; j < 4; ++j)
          acc[i][j] = __builtin_amdgcn_mfma_f32_16x16x32_bf16(af[i], bfm[j],
                                                              acc[i][j], 0, 0, 0);
    }
    __syncthreads();
  }

  const int b = m0 >> 12, trow = m0 & 4095;
  const bool isV = (n0 >= 512);
  float bv[4];
#pragma unroll
  for (int j = 0; j < 4; ++j) bv[j] = bias[n0 + nw + 16 * j + l15];

  if (isV) {
    f16* ET = (f16*)smem;
#pragma unroll
    for (int i = 0; i < 4; ++i)
#pragma unroll
      for (int j = 0; j < 4; ++j) {
        const int n = nw + 16 * j + l15, t = mw + 16 * i + quad * 4;
        f16x4 hv;
#pragma unroll
        for (int r = 0; r < 4; ++r) hv[r] = (f16)(acc[i][j][r] + bv[j]);
        *(f16x4*)(ET + n * 132 + t) = hv;
      }
    __syncthreads();
    const int nr = tid >> 4, l4 = tid & 15;
    const int g32 = l4 >> 2, q8 = l4 & 3;
#pragma unroll
    for (int pass = 0; pass < 8; ++pass) {
      const int n = pass * 16 + nr;
      const int gn = n0 + n;
      const int h = (gn >> 6) & 3, d = gn & 63;
      const f16* srcr = ET + n * 132 + g32 * 32 + q8 * 4;
      const f16x4 lo = *(const f16x4*)(srcr);
      const f16x4 hi = *(const f16x4*)(srcr + 16);
      union { f16x4 h4[2]; f16x8 h8; } u;
      u.h4[0] = lo; u.h4[1] = hi;
      *(f16x8*)(vt + ((size_t)(b * 4 + h) * 64 + d) * 4096 + trow + l4 * 8) =
          u.h8;
    }
  } else {
    const bool isQ = (n0 < 256);
    const float sc = isQ ? QSCALE : 1.0f;
    bf16* ET = (bf16*)smem;
#pragma unroll
    for (int i = 0; i < 4; ++i)
#pragma unroll
      for (int j = 0; j < 4; ++j) {
        const int n = nw + 16 * j + l15;
#pragma unroll
        for (int r = 0; r < 4; ++r) {
          const int t = mw + 16 * i + quad * 4 + r;
          ET[t * 132 + n] = (bf16)((acc[i][j][r] + bv[j]) * sc);
        }
      }
    __syncthreads();
    bf16* qk = isQ ? qb : kb;
    const int nr = tid >> 4, l4 = tid & 15;
    const int gn = n0 + l4 * 8;
    const int h = (gn >> 6) & 3, d = gn & 63;
#pragma unroll
    for (int pass = 0; pass < 8; ++pass) {
      const int t = pass * 16 + nr;
      const bf16x4 lo = *(const bf16x4*)(ET + t * 132 + l4 * 8);
      const bf16x4 hi = *(const bf16x4*)(ET + t * 132 + l4 * 8 + 4);
      union { bf16x4 h4[2]; bf16x8 h8; } u;
      u.h4[0] = lo; u.h4[1] = hi;
      *(bf16x8*)(qk + ((size_t)(b * 4 + h) * 4096 + trow + t) * 64 + d) = u.h8;
    }
  }
}

// ---------------- flash attention: KV-split (z=3), gload_lds staging --------
// z in {0,1,2}: kv ranges 1344/1344/1408. Grid (32,16,3)=1536 blocks -> fills
// the 5-blocks/CU LDS cap (was exactly 4), overlapping ramp/tail.
__global__ __launch_bounds__(256, 2)
void attn_kernel(const bf16* __restrict__ q, const bf16* __restrict__ k,
                 const f16* __restrict__ vt, bf16* __restrict__ o0,
                 bf16* __restrict__ o1, bf16* __restrict__ o2,
                 float* __restrict__ pD) {
  const int tid = threadIdx.x;
  const int wave = tid >> 6, lane = tid & 63;
  const int quad = lane >> 4, l15 = lane & 15;
  const int bh = blockIdx.y;
  const int q0 = blockIdx.x * 128;
  const int z = blockIdx.z;
  const int kvbase = z * 1344;
  const int nit = (z == 2) ? 22 : 21;
  __shared__ bf16 lK[2][64 * 64];
  __shared__ f16  lV[2][64 * 64];

  bf16x8 qa0[2], qa1[2];
#pragma unroll
  for (int s = 0; s < 2; ++s) {
    const bf16* qp =
        q + ((size_t)bh * 4096 + q0 + wave * 32 + s * 16 + l15) * 64 + quad * 8;
    qa0[s] = *(const bf16x8*)(qp);
    qa1[s] = *(const bf16x8*)(qp + 32);
  }

  const int srow = lane >> 3;              // row within 8-row group
  const int sc = (lane & 7) ^ srow;        // swizzled 16B chunk
  const bf16* kbase = k + ((size_t)bh * 4096 + kvbase) * 64;
  const f16*  vbase = vt + (size_t)bh * 64 * 4096 + kvbase;

#define STAGE_KV(buf, it_)                                                     \
  {                                                                            \
    const bf16* ks_ = kbase + (size_t)(it_) * 4096;                            \
    const f16*  vs_ = vbase + (it_) * 64;                                      \
    _Pragma("unroll")                                                          \
    for (int i_ = 0; i_ < 2; ++i_) {                                           \
      const int r0_ = i_ * 32 + wave * 8;                                      \
      __builtin_amdgcn_global_load_lds(                                        \
          (const __attribute__((address_space(1))) void*)(                     \
              ks_ + (size_t)(r0_ + srow) * 64 + sc * 8),                       \
          (__attribute__((address_space(3))) void*)(lK[buf] + r0_ * 64),       \
          16, 0, 0);                                                           \
      __builtin_amdgcn_global_load_lds(                                        \
          (const __attribute__((address_space(1))) void*)(                     \
              vs_ + (size_t)(r0_ + srow) * 4096 + sc * 8),                     \
          (__attribute__((address_space(3))) void*)(lV[buf] + r0_ * 64),       \
          16, 0, 0);                                                           \
    }                                                                          \
  }

  STAGE_KV(0, 0);

  f32x4 accO[2][4] = {};
  f32x4 accD[2] = {};
  const f16x8 vone8 = {(f16)1.0f, (f16)1.0f, (f16)1.0f, (f16)1.0f,
                       (f16)1.0f, (f16)1.0f, (f16)1.0f, (f16)1.0f};

  for (int it = 0; it < nit; ++it) {
    const int cur = it & 1;
    __syncthreads();                 // drains the in-flight gload_lds (vmcnt 0)
    if (it + 1 < nit) STAGE_KV(cur ^ 1, it + 1);

    f32x4 sf[2][4];
    __builtin_amdgcn_s_setprio(1);
#pragma unroll
    for (int c = 0; c < 4; ++c) {
      const bf16x8 kb0 = *(const bf16x8*)(lK[cur] + swzi(c * 16 + l15, quad));
      const bf16x8 kb1 = *(const bf16x8*)(lK[cur] + swzi(c * 16 + l15, 4 + quad));
#pragma unroll
      for (int s = 0; s < 2; ++s) {
        f32x4 t = {};
        t = __builtin_amdgcn_mfma_f32_16x16x32_bf16(kb0, qa0[s], t, 0, 0, 0);
        t = __builtin_amdgcn_mfma_f32_16x16x32_bf16(kb1, qa1[s], t, 0, 0, 0);
        sf[s][c] = t;
      }
    }
    __builtin_amdgcn_s_setprio(0);

    f16x8 pa[2][2];
#pragma unroll
    for (int s = 0; s < 2; ++s)
#pragma unroll
      for (int c2 = 0; c2 < 2; ++c2) {
        union { fp16x2 h2[4]; f16x8 h8; } u;
        u.h2[0] = __builtin_amdgcn_cvt_pkrtz(EXP2(sf[s][2 * c2][0]),
                                             EXP2(sf[s][2 * c2][1]));
        u.h2[1] = __builtin_amdgcn_cvt_pkrtz(EXP2(sf[s][2 * c2][2]),
                                             EXP2(sf[s][2 * c2][3]));
        u.h2[2] = __builtin_amdgcn_cvt_pkrtz(EXP2(sf[s][2 * c2 + 1][0]),
                                             EXP2(sf[s][2 * c2 + 1][1]));
        u.h2[3] = __builtin_amdgcn_cvt_pkrtz(EXP2(sf[s][2 * c2 + 1][2]),
                                             EXP2(sf[s][2 * c2 + 1][3]));
        pa[s][c2] = u.h8;
      }

    __builtin_amdgcn_s_setprio(1);
#pragma unroll
    for (int s = 0; s < 2; ++s)
#pragma unroll
      for (int c2 = 0; c2 < 2; ++c2)
        accD[s] = __builtin_amdgcn_mfma_f32_16x16x32_f16(pa[s][c2], vone8,
                                                         accD[s], 0, 0, 0);

#pragma unroll
    for (int c2 = 0; c2 < 2; ++c2) {
#pragma unroll
      for (int n = 0; n < 4; ++n) {
        const f16x8 vb =
            *(const f16x8*)(lV[cur] + swzi(n * 16 + l15, c2 * 4 + quad));
#pragma unroll
        for (int s = 0; s < 2; ++s)
          accO[s][n] = __builtin_amdgcn_mfma_f32_16x16x32_f16(pa[s][c2], vb,
                                                              accO[s][n], 0, 0, 0);
      }
    }
    __builtin_amdgcn_s_setprio(0);
  }
#undef STAGE_KV

  bf16* po = (z == 0) ? o0 : ((z == 1) ? o1 : o2);
  const int b = bh >> 2, h = bh & 3;
#pragma unroll
  for (int s = 0; s < 2; ++s) {
    float inv[4];
#pragma unroll
    for (int r = 0; r < 4; ++r) inv[r] = 1.0f / accD[s][r];
#pragma unroll
    for (int r = 0; r < 4; ++r) {
      const int t = q0 + wave * 32 + s * 16 + quad * 4 + r;
      if (l15 == 0) pD[(size_t)(z * 16 + bh) * 4096 + t] = accD[s][r];
#pragma unroll
      for (int n = 0; n < 4; ++n)
        po[(size_t)(b * 4096 + t) * 256 + h * 64 + n * 16 + l15] =
            (bf16)(accO[s][n][r] * inv[r]);
    }
  }
}

// ---------------- FUSED: proj-GEMM + 3-way combine + LN1 + FFN1 -------------
__global__ __launch_bounds__(256, 2)
void ln1_ffn1_kernel(const bf16* __restrict__ A, const bf16* __restrict__ A2,
                     const bf16* __restrict__ A3, const float* __restrict__ pD,
                     const bf16* __restrict__ pwt, const float* __restrict__ pb,
                     const float* __restrict__ xres, const float* __restrict__ lw,
                     const float* __restrict__ lb, bf16* __restrict__ x1b,
                     const bf16* __restrict__ f1wt, const float* __restrict__ f1b,
                     bf16* __restrict__ ob) {
  const int tid = threadIdx.x;
  const int wave = tid >> 6, lane = tid & 63;
  const int quad = lane >> 4, l15 = lane & 15;
  const int m0 = blockIdx.x * 32;
  const int nw = wave * 64;
  __shared__ bf16 lA[32 * 64];
  __shared__ bf16 lB[256 * 64];
  __shared__ bf16 aT[4 * 32 * 64];
  __shared__ float lnsum[4][32];
  __shared__ float lnsq[4][32];
  __shared__ float lnstat[32][2];
  f32x4 acc[2][4] = {};

  // ---- phase A: proj GEMM with inline 3-way KV-split combine ----
  for (int kt = 0; kt < 4; ++kt) {
    const int k0 = kt * 64;
    {
      const int row = tid >> 3, cc = tid & 7;
      const int am = m0 + row;
      const int ab = am >> 12, at = am & 4095;
      const int bhi = ab * 4 + kt;
      const float d0 = pD[(size_t)bhi * 4096 + at];
      const float d1 = pD[(size_t)(16 + bhi) * 4096 + at];
      const float d2 = pD[(size_t)(32 + bhi) * 4096 + at];
      const float wsum = 1.0f / (d0 + d1 + d2);
      const float w0 = d0 * wsum, w1 = d1 * wsum, w2 = d2 * wsum;
      const bf16x8 a0 = *(const bf16x8*)(A  + (size_t)am * 256 + k0 + cc * 8);
      const bf16x8 a1 = *(const bf16x8*)(A2 + (size_t)am * 256 + k0 + cc * 8);
      const bf16x8 a2 = *(const bf16x8*)(A3 + (size_t)am * 256 + k0 + cc * 8);
      bf16x8 cv;
#pragma unroll
      for (int i = 0; i < 8; ++i)
        cv[i] = (bf16)((float)a0[i] * w0 + (float)a1[i] * w1 + (float)a2[i] * w2);
      *(bf16x8*)(lA + swzi(row, cc)) = cv;
    }
    stage_swz<256>(lB, pwt + k0, 256);
    __syncthreads();
#pragma unroll
    for (int ks = 0; ks < 2; ++ks) {
      bf16x8 af[2], bfm[4];
#pragma unroll
      for (int i = 0; i < 2; ++i)
        af[i] = *(const bf16x8*)(lA + swzi(i * 16 + l15, ks * 4 + quad));
#pragma unroll
      for (int j = 0; j < 4; ++j)
        bfm[j] = *(const bf16x8*)(lB + swzi(nw + j * 16 + l15, ks * 4 + quad));
#pragma unroll
      for (int i = 0; i < 2; ++i)
#pragma unroll
        for (int j = 0; j < 4; ++j)
          acc[i][j] = __builtin_amdgcn_mfma_f32_16x16x32_bf16(af[i], bfm[j],
                                                              acc[i][j], 0, 0, 0);
    }
    __syncthreads();
  }

  // ---- LN over full 256-col rows ----
  float bv[4], lwv[4], lbv[4];
#pragma unroll
  for (int j = 0; j < 4; ++j) {
    const int col = nw + 16 * j + l15;
    bv[j] = pb[col]; lwv[j] = lw[col]; lbv[j] = lb[col];
  }
#pragma unroll
  for (int i = 0; i < 2; ++i) {
    float ps[4] = {}, pq[4] = {};
#pragma unroll
    for (int j = 0; j < 4; ++j) {
#pragma unroll
      for (int r = 0; r < 4; ++r) {
        const int m = m0 + 16 * i + 4 * quad + r;
        const size_t ri = (size_t)m * 256 + nw + 16 * j + l15;
        const float v = acc[i][j][r] + bv[j] + xres[ri];
        acc[i][j][r] = v;
        ps[r] += v;
        pq[r] += v * v;
      }
    }
#pragma unroll
    for (int r = 0; r < 4; ++r) {
#pragma unroll
      for (int mm = 1; mm < 16; mm <<= 1) {
        ps[r] += __shfl_xor(ps[r], mm, 64);
        pq[r] += __shfl_xor(pq[r], mm, 64);
      }
      if (l15 == 0) {
        lnsum[wave][16 * i + 4 * quad + r] = ps[r];
        lnsq[wave][16 * i + 4 * quad + r] = pq[r];
      }
    }
  }
  __syncthreads();
  if (tid < 32) {
    const float s = lnsum[0][tid] + lnsum[1][tid] + lnsum[2][tid] + lnsum[3][tid];
    const float sq = lnsq[0][tid] + lnsq[1][tid] + lnsq[2][tid] + lnsq[3][tid];
    const float mean = s * (1.0f / 256.0f);
    const float var = sq * (1.0f / 256.0f) - mean * mean;
    lnstat[tid][0] = mean;
    lnstat[tid][1] = rsqrtf(var + 1e-5f);
  }
  __syncthreads();
#pragma unroll
  for (int i = 0; i < 2; ++i) {
#pragma unroll
    for (int r = 0; r < 4; ++r) {
      const int row = 16 * i + 4 * quad + r;
      const float mean = lnstat[row][0], rstd = lnstat[row][1];
#pragma unroll
      for (int j = 0; j < 4; ++j) {
        const float ov = (acc[i][j][r] - mean) * rstd * lwv[j] + lbv[j];
        const bf16 obf = (bf16)ov;
        const size_t gi = (size_t)(m0 + row) * 256 + nw + 16 * j + l15;
        x1b[gi] = obf;                          // ln2 residual (global)
        const int cg = 16 * j + l15;            // col within k-group = wave
        aT[wave * 2048 + row * 64 + ((((cg >> 3) ^ (row & 7))) << 3) + (cg & 7)]
            = obf;                              // FFN1 A operand (LDS)
      }
    }
  }
  __syncthreads();

  // ---- phase B: FFN1 (32 rows x 768 cols, K=256 from LDS) ----
  const int nwB = wave * 32;
#pragma unroll 1
  for (int nt = 0; nt < 6; ++nt) {
    f32x4 acc2[2][2] = {};
    const bf16* Bb = f1wt + (size_t)nt * 128 * 256;
#pragma unroll 1
    for (int kh = 0; kh < 2; ++kh) {
      stage_swz<128>(lB,        Bb + kh * 128, 256);
      stage_swz<128>(lB + 8192, Bb + kh * 128 + 64, 256);
      __syncthreads();
#pragma unroll
      for (int kk = 0; kk < 2; ++kk) {
        const bf16* aTk = aT + (kh * 2 + kk) * 2048;
        const bf16* lbk = lB + kk * 8192;
#pragma unroll
        for (int ks = 0; ks < 2; ++ks) {
          bf16x8 af[2], bfm[2];
#pragma unroll
          for (int i = 0; i < 2; ++i)
            af[i] = *(const bf16x8*)(aTk + swzi(i * 16 + l15, ks * 4 + quad));
#pragma unroll
          for (int j = 0; j < 2; ++j)
            bfm[j] = *(const bf16x8*)(lbk + swzi(nwB + j * 16 + l15, ks * 4 + quad));
#pragma unroll
          for (int i = 0; i < 2; ++i)
#pragma unroll
            for (int j = 0; j < 2; ++j)
              acc2[i][j] = __builtin_amdgcn_mfma_f32_16x16x32_bf16(
                  af[i], bfm[j], acc2[i][j], 0, 0, 0);
        }
      }
      __syncthreads();
    }
#pragma unroll
    for (int j = 0; j < 2; ++j) {
      const int gn = nt * 128 + nwB + 16 * j + l15;
      const float bs = f1b[gn];
#pragma unroll
      for (int i = 0; i < 2; ++i)
#pragma unroll
        for (int r = 0; r < 4; ++r) {
          const int m = m0 + 16 * i + quad * 4 + r;
          ob[(size_t)m * 768 + gn] = (bf16)gelu_exact(acc2[i][j][r] + bs);
        }
    }
  }
}

// ---------------- GEMM + bias + residual + LayerNorm fused (ln2) ------------
template <int KTILES, bool RESID_BF16, bool WRITE_F, bool WRITE_B>
__global__ __launch_bounds__(256, 3)
void gemm_ln_kernel(const bf16* __restrict__ A, const bf16* __restrict__ Wt,
                    const float* __restrict__ bias, const void* __restrict__ Rv,
                    const float* __restrict__ lw, const float* __restrict__ lb,
                    float* __restrict__ outf, bf16* __restrict__ outb) {
  const int tid = threadIdx.x;
  const int wave = tid >> 6, lane = tid & 63;
  const int quad = lane >> 4, l15 = lane & 15;
  const int m0 = blockIdx.x * 32;
  const int nw = wave * 64;
  const int K = KTILES * 64;
  __shared__ bf16 lA[32 * 64];
  __shared__ bf16 lB[256 * 64];
  __shared__ float lnsum[4][32];
  __shared__ float lnsq[4][32];
  __shared__ float lnstat[32][2];
  f32x4 acc[2][4] = {};

  for (int kt = 0; kt < KTILES; ++kt) {
    const int k0 = kt * 64;
    stage_swz<32>(lA, A + (size_t)m0 * K + k0, K);
    stage_swz<256>(lB, Wt + k0, K);
    __syncthreads();
#pragma unroll
    for (int ks = 0; ks < 2; ++ks) {
      bf16x8 af[2], bfm[4];
#pragma unroll
      for (int i = 0; i < 2; ++i)
        af[i] = *(const bf16x8*)(lA + swzi(i * 16 + l15, ks * 4 + quad));
#pragma unroll
      for (int j = 0; j < 4; ++j)
        bfm[j] = *(const bf16x8*)(lB + swzi(nw + j * 16 + l15, ks * 4 + quad));
#pragma unroll
      for (int i = 0; i < 2; ++i)
#pragma unroll
        for (int j = 0; j < 4; ++j)
          acc[i][j] = __builtin_amdgcn_mfma_f32_16x16x32_bf16(af[i], bfm[j],
                                                              acc[i][j], 0, 0, 0);
    }
    __syncthreads();
  }

  float bv[4], lwv[4], lbv[4];
#pragma unroll
  for (int j = 0; j < 4; ++j) {
    const int col = nw + 16 * j + l15;
    bv[j] = bias[col]; lwv[j] = lw[col]; lbv[j] = lb[col];
  }
#pragma unroll
  for (int i = 0; i < 2; ++i) {
    float ps[4] = {}, pq[4] = {};
#pragma unroll
    for (int j = 0; j < 4; ++j) {
#pragma unroll
      for (int r = 0; r < 4; ++r) {
        const int m = m0 + 16 * i + 4 * quad + r;
        const size_t ri = (size_t)m * 256 + nw + 16 * j + l15;
        const float rv = RESID_BF16 ? (float)((const bf16*)Rv)[ri]
                                    : ((const float*)Rv)[ri];
        const float v = acc[i][j][r] + bv[j] + rv;
        acc[i][j][r] = v;
        ps[r] += v;
        pq[r] += v * v;
      }
    }
#pragma unroll
    for (int r = 0; r < 4; ++r) {
#pragma unroll
      for (int mm = 1; mm < 16; mm <<= 1) {
        ps[r] += __shfl_xor(ps[r], mm, 64);
        pq[r] += __shfl_xor(pq[r], mm, 64);
      }
      if (l15 == 0) {
        lnsum[wave][16 * i + 4 * quad + r] = ps[r];
        lnsq[wave][16 * i + 4 * quad + r] = pq[r];
      }
    }
  }
  __syncthreads();
  if (tid < 32) {
    const float s = lnsum[0][tid] + lnsum[1][tid] + lnsum[2][tid] + lnsum[3][tid];
    const float sq = lnsq[0][tid] + lnsq[1][tid] + lnsq[2][tid] + lnsq[3][tid];
    const float mean = s * (1.0f / 256.0f);
    const float var = sq * (1.0f / 256.0f) - mean * mean;
    lnstat[tid][0] = mean;
    lnstat[tid][1] = rsqrtf(var + 1e-5f);
  }
  __syncthreads();
#pragma unroll
  for (int i = 0; i < 2; ++i) {
#pragma unroll
    for (int r = 0; r < 4; ++r) {
      const int row = 16 * i + 4 * quad + r;
      const float mean = lnstat[row][0], rstd = lnstat[row][1];
#pragma unroll
      for (int j = 0; j < 4; ++j) {
        const float ov = (acc[i][j][r] - mean) * rstd * lwv[j] + lbv[j];
        const size_t gi = (size_t)(m0 + row) * 256 + nw + 16 * j + l15;
        if constexpr (WRITE_F) outf[gi] = ov;
        if constexpr (WRITE_B) outb[gi] = (bf16)ov;
      }
    }
  }
}

extern "C" void kernel_launch(void* const* d_in, const int* in_sizes, int n_in,
                              void* d_out, int out_size, void* d_ws, size_t ws_size,
                              hipStream_t stream) {
  const float* x      = (const float*)d_in[0];
  const float* qkv_w  = (const float*)d_in[1];
  const float* qkv_b  = (const float*)d_in[2];
  const float* proj_w = (const float*)d_in[3];
  const float* proj_b = (const float*)d_in[4];
  const float* n1_w   = (const float*)d_in[5];
  const float* n1_b   = (const float*)d_in[6];
  const float* ffn_w1 = (const float*)d_in[7];
  const float* ffn_b1 = (const float*)d_in[8];
  const float* ffn_w2 = (const float*)d_in[9];
  const float* ffn_b2 = (const float*)d_in[10];
  const float* n2_w   = (const float*)d_in[11];
  const float* n2_b   = (const float*)d_in[12];
  float* out = (float*)d_out;

  char* ws = (char*)d_ws;
  bf16*  qwt  = (bf16*)(ws + 0);
  bf16*  pwt  = (bf16*)(ws + 393216);
  bf16*  f1wt = (bf16*)(ws + 524288);
  bf16*  f2wt = (bf16*)(ws + 917504);
  bf16*  qb   = (bf16*)(ws + 1310720);
  bf16*  kb   = (bf16*)(ws + 9699328);
  f16*   vtb  = (f16*)(ws + 18087936);
  bf16*  attn = (bf16*)(ws + 26476544);   // partial O (z=0)
  bf16*  x1b  = (bf16*)(ws + 34865152);
  bf16*  hbuf = (bf16*)(ws + 1310720);    // aliases qb/kb/vtb (dead by FFN1)
  bf16*  xb   = (bf16*)(ws + 34865152);   // aliases x1b (dead after QKV GEMM)
  bf16*  po1  = (bf16*)(ws + 43253760);   // partial O (z=1)
  bf16*  po2  = (bf16*)(ws + 51642368);   // partial O (z=2)
  float* pden = (float*)(ws + 60030976);  // denominators [3][16][4096] f32

  cvt_w_kernel<<<2208, 256, 0, stream>>>(qkv_w, qwt, proj_w, pwt,
                                         ffn_w1, f1wt, ffn_w2, f2wt, x, xb);
  gemm_qkv_kernel<<<dim3(6, 128), 256, 0, stream>>>(xb, qwt, qkv_b, qb, kb, vtb);
  attn_kernel<<<dim3(32, 16, 3), 256, 0, stream>>>(qb, kb, vtb, attn, po1, po2,
                                                   pden);
  ln1_ffn1_kernel<<<512, 256, 0, stream>>>(attn, po1, po2, pden, pwt, proj_b,
                                           x, n1_w, n1_b, x1b, f1wt, ffn_b1,
                                           hbuf);
  gemm_ln_kernel<12, true, true, false><<<512, 256, 0, stream>>>(
      hbuf, f2wt, ffn_b2, x1b, n2_w, n2_b, out, nullptr);
}